// Round 6
// baseline (334.746 us; speedup 1.0000x reference)
//
#include <hip/hip_runtime.h>
#include <float.h>
#include <math.h>

// Problem constants
#define B_SZ 1024
#define D_SZ 8192
#define C_SZ 345
#define F_SZ 512
#define PROTO_W 0.99f

// d_out layout (float32, flat, reference return order):
//   logits   [2048][345]  @ 0
//   new_proto[345][512]   @ 706560
//   scores   [345][345]   @ 883200
//   labels   [1024]       @ 1002225  (stored as float)
//   feats    [2048][512]  @ 1003249

// d_ws layout (bytes):
//   Xh  [2048][8192] bf16 @ 0          (33,554,432)
//   Xl  [2048][8192] bf16 @ 33554432
//   Wh  [512][8192]  bf16 @ 67108864   (tile-transposed: [n][k])
//   Wl  [512][8192]  bf16 @ 75497472
//   P   [2][2048][512] f32 @ 83886080  (split-K partials)
// Overlay region — reuses Xh space. ORDERING INVARIANT: everything below is
// written only AFTER gemm_ws128 has consumed Xh (R5 bug: convert_all wrote
// Wth before the GEMM ran, clobbering Xh rows 256-303 -> wrong labels).
//   Fh  [2048][512] bf16 @ 0          (reduce_feats_split)
//   Fl  [2048][512] bf16 @ 2097152    (reduce_feats_split)
//   Wth [384][512]  bf16 @ 4194304    (reduce_feats_split tail blocks)
//   Wtl [384][512]  bf16 @ 4587520
//   NPh [384][512]  bf16 @ 4980736    (proto_update)
//   NPl [384][512]  bf16 @ 5373952
#define WS_XH 0
#define WS_XL 33554432u
#define WS_WH 67108864u
#define WS_WL 75497472u
#define WS_P  83886080u
#define WS_NEED 92274688u
#define WS_FH  0u
#define WS_FL  2097152u
#define WS_WFH 4194304u
#define WS_WFL 4587520u
#define WS_NPH 4980736u
#define WS_NPL 5373952u

typedef short bf16x8 __attribute__((ext_vector_type(8)));
typedef short short4v __attribute__((ext_vector_type(4)));
typedef short short8v __attribute__((ext_vector_type(8)));
typedef float f32x4  __attribute__((ext_vector_type(4)));

__device__ __forceinline__ void split_bf16(float x, short& hi, short& lo) {
    unsigned u = __float_as_uint(x);
    unsigned r = (u + 0x7FFFu + ((u >> 16) & 1u)) >> 16;
    hi = (short)r;
    float hf = __uint_as_float(r << 16);
    lo = (short)(__float_as_uint(x - hf) >> 16);
}

__device__ __forceinline__ void gl_lds16(const short* g, short* l) {
    __builtin_amdgcn_global_load_lds(
        (const __attribute__((address_space(1))) void*)g,
        (__attribute__((address_space(3))) void*)l, 16, 0, 0);
}

#define MFMA_BF16 __builtin_amdgcn_mfma_f32_16x16x32_bf16

// 12-MFMA bf16x3 block (2x2 frags) for the 64-tile gemm_fc kernel.
#define MFMA_BLOCK(IA0, IA1, IB0, IB1)                                   \
    do {                                                                 \
        bf16x8 a0h = *(const bf16x8*)&sAh[IA0];                          \
        bf16x8 a1h = *(const bf16x8*)&sAh[IA1];                          \
        bf16x8 b0h = *(const bf16x8*)&sBh[IB0];                          \
        bf16x8 b1h = *(const bf16x8*)&sBh[IB1];                          \
        bf16x8 a0l = *(const bf16x8*)&sAl[IA0];                          \
        bf16x8 a1l = *(const bf16x8*)&sAl[IA1];                          \
        bf16x8 b0l = *(const bf16x8*)&sBl[IB0];                          \
        bf16x8 b1l = *(const bf16x8*)&sBl[IB1];                          \
        acc[0][0] = MFMA_BF16(a0h, b0h, acc[0][0], 0, 0, 0);             \
        acc[0][1] = MFMA_BF16(a0h, b1h, acc[0][1], 0, 0, 0);             \
        acc[1][0] = MFMA_BF16(a1h, b0h, acc[1][0], 0, 0, 0);             \
        acc[1][1] = MFMA_BF16(a1h, b1h, acc[1][1], 0, 0, 0);             \
        acc[0][0] = MFMA_BF16(a0h, b0l, acc[0][0], 0, 0, 0);             \
        acc[0][1] = MFMA_BF16(a0h, b1l, acc[0][1], 0, 0, 0);             \
        acc[1][0] = MFMA_BF16(a1h, b0l, acc[1][0], 0, 0, 0);             \
        acc[1][1] = MFMA_BF16(a1h, b1l, acc[1][1], 0, 0, 0);             \
        acc[0][0] = MFMA_BF16(a0l, b0h, acc[0][0], 0, 0, 0);             \
        acc[0][1] = MFMA_BF16(a0l, b1h, acc[0][1], 0, 0, 0);             \
        acc[1][0] = MFMA_BF16(a1l, b0h, acc[1][0], 0, 0, 0);             \
        acc[1][1] = MFMA_BF16(a1l, b1h, acc[1][1], 0, 0, 0);             \
    } while (0)

// ---------------------------------------------------------------------------
// convert_all: X and W_enc conversion ONLY (W_fc conversion deferred to
// reduce_feats_split so it lands in the overlay AFTER gemm_ws128 reads Xh).
//   blocks [0,1024):    X fp32 -> Xh/Xl (grid-stride)
//   blocks [1024,2048): W_enc [k][n] -> Wh/Wl [n][k] (64x64 transpose tiles)
// ---------------------------------------------------------------------------
__global__ __launch_bounds__(256) void convert_all(
    const float* __restrict__ img_q, const float* __restrict__ img_q1,
    const float* __restrict__ W_enc,
    short* __restrict__ Xh, short* __restrict__ Xl,
    short* __restrict__ Wh, short* __restrict__ Wl)
{
    __shared__ float tile[64][65];
    const int bid = blockIdx.x;
    const int t = threadIdx.x;

    if (bid < 1024) {
        const int HALF = (B_SZ * D_SZ) / 4;
        const int total = 2 * HALF;
        for (int i4 = bid * 256 + t; i4 < total; i4 += 1024 * 256) {
            float4 v = (i4 < HALF) ? ((const float4*)img_q)[i4]
                                   : ((const float4*)img_q1)[i4 - HALF];
            short4v h, l;
            short hh, ll;
            split_bf16(v.x, hh, ll); h.x = hh; l.x = ll;
            split_bf16(v.y, hh, ll); h.y = hh; l.y = ll;
            split_bf16(v.z, hh, ll); h.z = hh; l.z = ll;
            split_bf16(v.w, hh, ll); h.w = hh; l.w = ll;
            ((short4v*)Xh)[i4] = h;
            ((short4v*)Xl)[i4] = l;
        }
    } else {
        const int id = bid - 1024;
        const int k0 = (id >> 3) * 64;
        const int n0 = (id & 7) * 64;
        {
            const int kr = t >> 2;
            const int cb = (t & 3) * 16;
#pragma unroll
            for (int j = 0; j < 4; ++j) {
                float4 v = *(const float4*)&W_enc[(size_t)(k0 + kr) * F_SZ + n0 + cb + j * 4];
                tile[kr][cb + j * 4 + 0] = v.x;
                tile[kr][cb + j * 4 + 1] = v.y;
                tile[kr][cb + j * 4 + 2] = v.z;
                tile[kr][cb + j * 4 + 3] = v.w;
            }
        }
        __syncthreads();
        const int n = t >> 2;
#pragma unroll
        for (int cc = 0; cc < 2; ++cc) {
            const int ch = (t & 3) * 2 + cc;
            short8v h, l;
#pragma unroll
            for (int e = 0; e < 8; ++e) {
                short hh, ll;
                split_bf16(tile[ch * 8 + e][n], hh, ll);
                h[e] = hh; l[e] = ll;
            }
            size_t off = (size_t)(n0 + n) * D_SZ + k0 + ch * 8;
            *(short8v*)&Wh[off] = h;
            *(short8v*)&Wl[off] = l;
        }
    }
}

// ---------------------------------------------------------------------------
// gemm_ws128: P[ks] = A(128 x 4096) @ B(4096 x 128), bf16x3, split-K=2.
// 128x128 tile, BK=64, 256 threads = 4 waves, each a 64x64 quadrant
// (4x4 fragment grid, 48 MFMA per 32-k sub-tile per wave).
// Double-buffered LDS (128 KB), global_load_lds dwordx4 staging, XOR-swizzled
// k-chunks (conflict-free, verified 0 conflicts in the 64-tile version).
// grid (4, 16, 2) = 128 blocks. Memory-traffic-bound: 512 MB logical reads
// (half of the 64-tile version).
// ---------------------------------------------------------------------------
__global__ __launch_bounds__(256, 1) void gemm_ws128(
    const short* __restrict__ Xh, const short* __restrict__ Xl,
    const short* __restrict__ Wh, const short* __restrict__ Wl,
    float* __restrict__ P)
{
    __shared__ __align__(16) short sAh[2][8192];
    __shared__ __align__(16) short sAl[2][8192];
    __shared__ __align__(16) short sBh[2][8192];
    __shared__ __align__(16) short sBl[2][8192];

    const int t = threadIdx.x;
    const int lane = t & 63;
    const int wave = t >> 6;
    const int nt = blockIdx.x;          // 0..3
    const int mt = blockIdx.y;          // 0..15
    const int ks = blockIdx.z;          // 0..1
    const int m0 = mt * 128;
    const int n0 = nt * 128;
    const int kbase = ks * 4096;

    // staging role: wave 0->sAh, 1->sAl, 2->sBh, 3->sBl (16 KB each, 16 issues)
    const short* gbase =
        (wave == 0) ? Xh + (size_t)m0 * D_SZ :
        (wave == 1) ? Xl + (size_t)m0 * D_SZ :
        (wave == 2) ? Wh + (size_t)n0 * D_SZ :
                      Wl + (size_t)n0 * D_SZ;
    short* lb[2];
    lb[0] = (wave == 0) ? sAh[0] : (wave == 1) ? sAl[0] : (wave == 2) ? sBh[0] : sBl[0];
    lb[1] = (wave == 0) ? sAh[1] : (wave == 1) ? sAl[1] : (wave == 2) ? sBh[1] : sBl[1];
    const int lrow8 = lane >> 3;                       // 0..7
    const int gchunkOff = ((lane & 7) ^ lrow8) * 8;    // XOR swizzle on global side
    const short* gsrc = gbase + (size_t)lrow8 * D_SZ + kbase + gchunkOff;

    // MFMA coords: wave quadrant 64x64
    const int mo = (wave >> 1) * 64;
    const int no = (wave & 1) * 64;
    const int lr = lane & 15;
    const int lkg = lane >> 4;          // 0..3
    const int x7 = lr & 7;
    const int sl0 = lkg ^ x7;           // k-sub 0 chunk slot
    const int sl1 = (4 + lkg) ^ x7;     // k-sub 1 chunk slot
    int aoff[4], boff[4];
#pragma unroll
    for (int f = 0; f < 4; ++f) {
        aoff[f] = (mo + 16 * f + lr) * 64;
        boff[f] = (no + 16 * f + lr) * 64;
    }

    f32x4 acc[4][4] = {};

    // prologue: stage step 0 into buffer 0
#pragma unroll
    for (int j = 0; j < 16; ++j)
        gl_lds16(gsrc + (size_t)(8 * j) * D_SZ, lb[0] + j * 512);
    __syncthreads();

    int buf = 0;
    for (int s = 0; s < 64; ++s) {
        // issue next step's staging into the other buffer (flies under MFMA)
        if (s + 1 < 64) {
            short* dst = lb[buf ^ 1];
            const short* g = gsrc + (s + 1) * 64;
#pragma unroll
            for (int j = 0; j < 16; ++j)
                gl_lds16(g + (size_t)(8 * j) * D_SZ, dst + j * 512);
        }
        const short* pAh = sAh[buf];
        const short* pAl = sAl[buf];
        const short* pBh = sBh[buf];
        const short* pBl = sBl[buf];
#pragma unroll
        for (int ksub = 0; ksub < 2; ++ksub) {
            const int sl = ksub ? sl1 : sl0;
            bf16x8 ah[4], al[4], bh[4], blo[4];
#pragma unroll
            for (int f = 0; f < 4; ++f) {
                ah[f]  = *(const bf16x8*)&pAh[aoff[f] + sl * 8];
                al[f]  = *(const bf16x8*)&pAl[aoff[f] + sl * 8];
            }
#pragma unroll
            for (int g = 0; g < 4; ++g) {
                bh[g]  = *(const bf16x8*)&pBh[boff[g] + sl * 8];
                blo[g] = *(const bf16x8*)&pBl[boff[g] + sl * 8];
            }
#pragma unroll
            for (int f = 0; f < 4; ++f)
#pragma unroll
                for (int g = 0; g < 4; ++g)
                    acc[f][g] = MFMA_BF16(ah[f], bh[g], acc[f][g], 0, 0, 0);
#pragma unroll
            for (int f = 0; f < 4; ++f)
#pragma unroll
                for (int g = 0; g < 4; ++g)
                    acc[f][g] = MFMA_BF16(ah[f], blo[g], acc[f][g], 0, 0, 0);
#pragma unroll
            for (int f = 0; f < 4; ++f)
#pragma unroll
                for (int g = 0; g < 4; ++g)
                    acc[f][g] = MFMA_BF16(al[f], bh[g], acc[f][g], 0, 0, 0);
        }
        __syncthreads();   // drains staging vmcnt; protects buf re-write
        buf ^= 1;
    }

    float* Pout = P + (size_t)ks * (2048u * 512u);
#pragma unroll
    for (int f = 0; f < 4; ++f)
#pragma unroll
        for (int g = 0; g < 4; ++g) {
            const int col  = n0 + no + 16 * g + (lane & 15);
            const int row0 = m0 + mo + 16 * f + (lane >> 4) * 4;
#pragma unroll
            for (int r = 0; r < 4; ++r)
                Pout[(size_t)(row0 + r) * F_SZ + col] = acc[f][g][r];
        }
}

// ---------------------------------------------------------------------------
// reduce_feats_split: blocks [0,1024): feats = P0 + P1 (fp32) plus Fh/Fl bf16
// hi/lo. blocks [1024,1072): W_fc [k][c] -> Wth/Wtl [c][k] transpose+split
// (runs AFTER gemm_ws128, so writing into the Xh overlay is safe).
// ---------------------------------------------------------------------------
__global__ __launch_bounds__(256) void reduce_feats_split(
    const float* __restrict__ P, float* __restrict__ feats,
    short* __restrict__ Fh, short* __restrict__ Fl,
    const float* __restrict__ W_fc,
    short* __restrict__ Wth, short* __restrict__ Wtl)
{
    const int bid = blockIdx.x;
    const int t = threadIdx.x;
    if (bid < 1024) {
        const int n4 = (2048 * 512) / 4;
        const float* P1 = P + 2048 * 512;
        for (int i4 = bid * 256 + t; i4 < n4; i4 += 1024 * 256) {
            float4 a = ((const float4*)P)[i4];
            float4 b = ((const float4*)P1)[i4];
            float v[4] = {a.x + b.x, a.y + b.y, a.z + b.z, a.w + b.w};
            short4v h, l;
            short hh, ll;
#pragma unroll
            for (int e = 0; e < 4; ++e) {
                feats[i4 * 4 + e] = v[e];
                split_bf16(v[e], hh, ll); h[e] = hh; l[e] = ll;
            }
            ((short4v*)Fh)[i4] = h;
            ((short4v*)Fl)[i4] = l;
        }
    } else {
        __shared__ float tile[64][65];
        const int id = bid - 1024;           // 0..47
        const int k0 = (id & 7) * 64;
        const int c0 = (id >> 3) * 64;
        for (int idx = t; idx < 64 * 64; idx += 256) {
            const int kr = idx >> 6;
            const int cc = idx & 63;
            tile[kr][cc] = (c0 + cc < C_SZ) ? W_fc[(size_t)(k0 + kr) * C_SZ + c0 + cc] : 0.0f;
        }
        __syncthreads();
        const int crow = t >> 2;
#pragma unroll
        for (int cc2 = 0; cc2 < 2; ++cc2) {
            const int ch = (t & 3) * 2 + cc2;
            short8v h, l;
#pragma unroll
            for (int e = 0; e < 8; ++e) {
                short hh, ll;
                split_bf16(tile[ch * 8 + e][crow], hh, ll);
                h[e] = hh; l[e] = ll;
            }
            size_t off = (size_t)(c0 + crow) * F_SZ + k0 + ch * 8;
            *(short8v*)&Wth[off] = h;
            *(short8v*)&Wtl[off] = l;
        }
    }
}

// ---------------------------------------------------------------------------
// gemm_fc: Cout[M][345] = A[M][512] @ B^T (B = [384][512] row-per-col) + bias
// bf16x3 MFMA, 64x64 tile, BK=64 x 8 steps. grid (6, ceil(M/64)).
// ---------------------------------------------------------------------------
__global__ __launch_bounds__(256) void gemm_fc(
    const short* __restrict__ Ah, const short* __restrict__ Al,
    const short* __restrict__ Bh, const short* __restrict__ Bl,
    const float* __restrict__ bias, float* __restrict__ Cout, int M)
{
    __shared__ __align__(16) short sAh[4096];
    __shared__ __align__(16) short sAl[4096];
    __shared__ __align__(16) short sBh[4096];
    __shared__ __align__(16) short sBl[4096];

    const int t = threadIdx.x;
    const int lane = t & 63;
    const int wave = t >> 6;
    const int n0 = blockIdx.x * 64;
    const int m0 = blockIdx.y * 64;

    const int lrow8 = lane >> 3;
    const int colOff = ((lane & 7) ^ lrow8) * 8;

    short* lbase = (wave == 0) ? sAh : (wave == 1) ? sAl : (wave == 2) ? sBh : sBl;
    const short* gA = (wave == 1) ? Al : Ah;
    const short* gB = (wave == 3) ? Bl : Bh;
    const bool isA = wave < 2;

    const int mo = (wave >> 1) * 32;
    const int no = (wave & 1) * 32;
    const int lr = lane & 15;
    const int lkg = lane >> 4;
    const int x7 = lr & 7;
    const int sl0 = (0 + lkg) ^ x7;
    const int sl1 = (4 + lkg) ^ x7;
    const int ra0 = (mo + lr) * 64,      ra1 = (mo + 16 + lr) * 64;
    const int rb0 = (no + lr) * 64,      rb1 = (no + 16 + lr) * 64;
    const int a00 = ra0 + sl0 * 8, a01 = ra0 + sl1 * 8;
    const int a10 = ra1 + sl0 * 8, a11 = ra1 + sl1 * 8;
    const int b00 = rb0 + sl0 * 8, b01 = rb0 + sl1 * 8;
    const int b10 = rb1 + sl0 * 8, b11 = rb1 + sl1 * 8;

    f32x4 acc[2][2] = {};

    for (int s = 0; s < 8; ++s) {
        __syncthreads();
        if (isA) {
#pragma unroll
            for (int j = 0; j < 8; ++j) {
                int row = m0 + lrow8 + 8 * j;
                if (row > M - 1) row = M - 1;
                gl_lds16(gA + (size_t)row * F_SZ + s * 64 + colOff, lbase + j * 512);
            }
        } else {
#pragma unroll
            for (int j = 0; j < 8; ++j) {
                int row = n0 + lrow8 + 8 * j;   // < 384, allocated
                gl_lds16(gB + (size_t)row * F_SZ + s * 64 + colOff, lbase + j * 512);
            }
        }
        __syncthreads();
        MFMA_BLOCK(a00, a10, b00, b10);
        MFMA_BLOCK(a01, a11, b01, b11);
    }

#pragma unroll
    for (int f = 0; f < 2; ++f)
#pragma unroll
        for (int g = 0; g < 2; ++g) {
            const int col  = n0 + no + g * 16 + (lane & 15);
            if (col >= C_SZ) continue;
            const float bb = bias[col];
            const int row0 = m0 + mo + f * 16 + (lane >> 4) * 4;
#pragma unroll
            for (int r = 0; r < 4; ++r) {
                const int row = row0 + r;
                if (row < M)
                    Cout[(size_t)row * C_SZ + col] = acc[f][g][r] + bb;
            }
        }
}

// ---------------------------------------------------------------------------
// argmax_labels: masked argmax per row (softmax+renorm preserve argmax).
// ---------------------------------------------------------------------------
__global__ __launch_bounds__(64) void argmax_labels(
    const float* __restrict__ logits, const float* __restrict__ partial_Y,
    float* __restrict__ labels_f)
{
    const int i = blockIdx.x;
    const int lane = threadIdx.x;
    float best = -FLT_MAX;
    int bidx = C_SZ;
    for (int c = lane; c < C_SZ; c += 64) {
        if (partial_Y[(size_t)i * C_SZ + c] != 0.0f) {
            float v = logits[(size_t)i * C_SZ + c];
            if (v > best || (v == best && c < bidx)) { best = v; bidx = c; }
        }
    }
#pragma unroll
    for (int off = 32; off; off >>= 1) {
        float ov = __shfl_down(best, off);
        int oi = __shfl_down(bidx, off);
        if (ov > best || (ov == best && oi < bidx)) { best = ov; bidx = oi; }
    }
    if (lane == 0) labels_f[i] = (float)bidx;
}

// ---------------------------------------------------------------------------
// proto_update: literal sequential EMA per class, L2 renorm; also emits
// bf16 hi/lo of new_proto for the scores MFMA (if NPh != nullptr).
// ---------------------------------------------------------------------------
__global__ __launch_bounds__(512) void proto_update(
    const float* __restrict__ labels_f, const float* __restrict__ feats_q,
    const float* __restrict__ proto, float* __restrict__ new_proto,
    short* __restrict__ NPh, short* __restrict__ NPl)
{
    __shared__ int lab[B_SZ];
    __shared__ float red[8];
    __shared__ float rinv_s;
    const int c = blockIdx.x;
    const int t = threadIdx.x;
    for (int i = t; i < B_SZ; i += 512) lab[i] = (int)labels_f[i];
    __syncthreads();
    float val = proto[(size_t)c * F_SZ + t];
    for (int i = 0; i < B_SZ; ++i) {
        if (lab[i] == c)
            val = PROTO_W * val + (1.0f - PROTO_W) * feats_q[(size_t)i * F_SZ + t];
    }
    float sq = val * val;
#pragma unroll
    for (int off = 32; off; off >>= 1) sq += __shfl_down(sq, off);
    if ((t & 63) == 0) red[t >> 6] = sq;
    __syncthreads();
    if (t == 0) {
        float s = 0.0f;
#pragma unroll
        for (int w = 0; w < 8; ++w) s += red[w];
        rinv_s = 1.0f / sqrtf(s);
    }
    __syncthreads();
    const float v = val * rinv_s;
    new_proto[(size_t)c * F_SZ + t] = v;
    if (NPh) {
        short hh, ll;
        split_bf16(v, hh, ll);
        NPh[(size_t)c * F_SZ + t] = hh;
        NPl[(size_t)c * F_SZ + t] = ll;
    }
}

// ---------------------------------------------------------------------------
// Fallback path kernels (only if ws_size is insufficient) — proven R2/R3 code.
// ---------------------------------------------------------------------------
#define LDA 40
__global__ __launch_bounds__(256) void gemm_enc_mfma(
    const float* __restrict__ img_q, const float* __restrict__ img_q1,
    const float* __restrict__ W_enc, float* __restrict__ feats)
{
    __shared__ __align__(16) short Ah[2][64 * LDA];
    __shared__ __align__(16) short Al[2][64 * LDA];
    __shared__ __align__(16) short Bh[2][64 * LDA];
    __shared__ __align__(16) short Bl[2][64 * LDA];
    const int t = threadIdx.x;
    const int nBase = blockIdx.x * 64;
    const int mBase = blockIdx.y * 64;
    const float* X = (mBase < B_SZ) ? (img_q + (size_t)mBase * D_SZ)
                                    : (img_q1 + (size_t)(mBase - B_SZ) * D_SZ);
    const int arow = t >> 2;
    const int akq  = t & 3;
    const int bn   = t & 63;
    const int bkg  = t >> 6;
    const int bsw  = (bkg + (bn >> 3)) & 3;
    const float* aptr = X + (size_t)arow * D_SZ + akq * 8;
    const float* bptr = W_enc + (size_t)(bkg * 8) * F_SZ + nBase + bn;
    const int wave = t >> 6;
    const int lane = t & 63;
    const int mo   = (wave >> 1) * 32;
    const int no   = (wave & 1) * 32;
    const int lrow = lane & 15;
    const int lkg  = lane >> 4;
    f32x4 acc[2][2] = {};
    {
        float4 av0 = *(const float4*)(aptr);
        float4 av1 = *(const float4*)(aptr + 4);
        float bv[8];
#pragma unroll
        for (int i = 0; i < 8; ++i) bv[i] = bptr[(size_t)i * F_SZ];
        bf16x8 h, l;
        float va[8] = {av0.x, av0.y, av0.z, av0.w, av1.x, av1.y, av1.z, av1.w};
#pragma unroll
        for (int i = 0; i < 8; ++i) { short hh, ll; split_bf16(va[i], hh, ll); h[i] = hh; l[i] = ll; }
        *(bf16x8*)&Ah[0][arow * LDA + akq * 8] = h;
        *(bf16x8*)&Al[0][arow * LDA + akq * 8] = l;
#pragma unroll
        for (int i = 0; i < 8; ++i) { short hh, ll; split_bf16(bv[i], hh, ll); h[i] = hh; l[i] = ll; }
        *(bf16x8*)&Bh[0][bn * LDA + bsw * 8] = h;
        *(bf16x8*)&Bl[0][bn * LDA + bsw * 8] = l;
    }
    __syncthreads();
    const int aoff0 = (mo + lrow) * LDA + lkg * 8;
    const int aoff1 = (mo + 16 + lrow) * LDA + lkg * 8;
    const int bnn0  = no + lrow;
    const int bnn1  = no + 16 + lrow;
    const int boff0 = bnn0 * LDA + ((lkg + (bnn0 >> 3)) & 3) * 8;
    const int boff1 = bnn1 * LDA + ((lkg + (bnn1 >> 3)) & 3) * 8;
    int buf = 0;
    for (int s = 0; s < 256; ++s) {
        float4 na0, na1; float nb[8];
        const bool more = (s + 1 < 256);
        if (more) {
            const float* ap = aptr + (size_t)(s + 1) * 32;
            na0 = *(const float4*)(ap);
            na1 = *(const float4*)(ap + 4);
            const float* bp = bptr + (size_t)(s + 1) * 32 * F_SZ;
#pragma unroll
            for (int i = 0; i < 8; ++i) nb[i] = bp[(size_t)i * F_SZ];
        }
        bf16x8 a0h = *(bf16x8*)&Ah[buf][aoff0];
        bf16x8 a1h = *(bf16x8*)&Ah[buf][aoff1];
        bf16x8 a0l = *(bf16x8*)&Al[buf][aoff0];
        bf16x8 a1l = *(bf16x8*)&Al[buf][aoff1];
        bf16x8 b0h = *(bf16x8*)&Bh[buf][boff0];
        bf16x8 b1h = *(bf16x8*)&Bh[buf][boff1];
        bf16x8 b0l = *(bf16x8*)&Bl[buf][boff0];
        bf16x8 b1l = *(bf16x8*)&Bl[buf][boff1];
        acc[0][0] = MFMA_BF16(a0h, b0h, acc[0][0], 0, 0, 0);
        acc[0][1] = MFMA_BF16(a0h, b1h, acc[0][1], 0, 0, 0);
        acc[1][0] = MFMA_BF16(a1h, b0h, acc[1][0], 0, 0, 0);
        acc[1][1] = MFMA_BF16(a1h, b1h, acc[1][1], 0, 0, 0);
        acc[0][0] = MFMA_BF16(a0h, b0l, acc[0][0], 0, 0, 0);
        acc[0][1] = MFMA_BF16(a0h, b1l, acc[0][1], 0, 0, 0);
        acc[1][0] = MFMA_BF16(a1h, b0l, acc[1][0], 0, 0, 0);
        acc[1][1] = MFMA_BF16(a1h, b1l, acc[1][1], 0, 0, 0);
        acc[0][0] = MFMA_BF16(a0l, b0h, acc[0][0], 0, 0, 0);
        acc[0][1] = MFMA_BF16(a0l, b1h, acc[0][1], 0, 0, 0);
        acc[1][0] = MFMA_BF16(a1l, b0h, acc[1][0], 0, 0, 0);
        acc[1][1] = MFMA_BF16(a1l, b1h, acc[1][1], 0, 0, 0);
        if (more) {
            bf16x8 h, l;
            float va[8] = {na0.x, na0.y, na0.z, na0.w, na1.x, na1.y, na1.z, na1.w};
#pragma unroll
            for (int i = 0; i < 8; ++i) { short hh, ll; split_bf16(va[i], hh, ll); h[i] = hh; l[i] = ll; }
            *(bf16x8*)&Ah[buf ^ 1][arow * LDA + akq * 8] = h;
            *(bf16x8*)&Al[buf ^ 1][arow * LDA + akq * 8] = l;
#pragma unroll
            for (int i = 0; i < 8; ++i) { short hh, ll; split_bf16(nb[i], hh, ll); h[i] = hh; l[i] = ll; }
            *(bf16x8*)&Bh[buf ^ 1][bn * LDA + bsw * 8] = h;
            *(bf16x8*)&Bl[buf ^ 1][bn * LDA + bsw * 8] = l;
        }
        __syncthreads();
        buf ^= 1;
    }
#pragma unroll
    for (int f = 0; f < 2; ++f)
#pragma unroll
        for (int g = 0; g < 2; ++g) {
            const int col  = nBase + no + g * 16 + (lane & 15);
            const int row0 = mBase + mo + f * 16 + (lane >> 4) * 4;
#pragma unroll
            for (int r = 0; r < 4; ++r)
                feats[(size_t)(row0 + r) * F_SZ + col] = acc[f][g][r];
        }
}

__global__ __launch_bounds__(256) void fc_logits_fused(
    const float* __restrict__ feats, const float* __restrict__ W_fc,
    const float* __restrict__ b_fc, const float* __restrict__ partial_Y,
    float* __restrict__ logits, float* __restrict__ labels_f)
{
    __shared__ __align__(16) float fs[4][F_SZ];
    __shared__ float redv[4];
    __shared__ int   redi[4];
    const int t = threadIdx.x;
    const int r0 = blockIdx.x * 4;
#pragma unroll
    for (int j = 0; j < 2; ++j) {
        int f4 = t + j * 256;
        int row = f4 >> 7;
        int col = (f4 & 127) * 4;
        *(float4*)&fs[row][col] = *(const float4*)&feats[(size_t)(r0 + row) * F_SZ + col];
    }
    __syncthreads();
    const int c0 = t;
    const int c1 = t + 256;
    float acc0[4] = {};
    float acc1[4] = {};
#pragma unroll 4
    for (int k = 0; k < F_SZ; ++k) {
        float w0 = W_fc[k * C_SZ + c0];
        float w1 = (c1 < C_SZ) ? W_fc[k * C_SZ + c1] : 0.0f;
#pragma unroll
        for (int r = 0; r < 4; ++r) {
            float f = fs[r][k];
            acc0[r] += f * w0;
            acc1[r] += f * w1;
        }
    }
    float v0[4], v1[4];
    const float bb0 = b_fc[c0];
    const float bb1 = (c1 < C_SZ) ? b_fc[c1] : 0.0f;
#pragma unroll
    for (int r = 0; r < 4; ++r) {
        v0[r] = acc0[r] + bb0;
        logits[(size_t)(r0 + r) * C_SZ + c0] = v0[r];
        if (c1 < C_SZ) {
            v1[r] = acc1[r] + bb1;
            logits[(size_t)(r0 + r) * C_SZ + c1] = v1[r];
        }
    }
    if (r0 < B_SZ) {
#pragma unroll
        for (int r = 0; r < 4; ++r) {
            const int row = r0 + r;
            float best = -FLT_MAX; int bi = C_SZ;
            if (partial_Y[(size_t)row * C_SZ + c0] != 0.0f) { best = v0[r]; bi = c0; }
            if (c1 < C_SZ && partial_Y[(size_t)row * C_SZ + c1] != 0.0f && v1[r] > best) {
                best = v1[r]; bi = c1;
            }
#pragma unroll
            for (int off = 32; off; off >>= 1) {
                float ov = __shfl_down(best, off);
                int oi = __shfl_down(bi, off);
                if (ov > best || (ov == best && oi < bi)) { best = ov; bi = oi; }
            }
            if ((t & 63) == 0) { redv[t >> 6] = best; redi[t >> 6] = bi; }
            __syncthreads();
            if (t == 0) {
                float bb = redv[0]; int ii = redi[0];
#pragma unroll
                for (int w = 1; w < 4; ++w)
                    if (redv[w] > bb || (redv[w] == bb && redi[w] < ii)) { bb = redv[w]; ii = redi[w]; }
                labels_f[row] = (float)ii;
            }
            __syncthreads();
        }
    }
}

__global__ __launch_bounds__(256) void fc_proto(
    const float* __restrict__ new_proto, const float* __restrict__ W_fc,
    const float* __restrict__ b_fc, float* __restrict__ scores)
{
    __shared__ __align__(16) float ps[8][F_SZ];
    const int t = threadIdx.x;
    const int r0 = blockIdx.x * 8;
#pragma unroll
    for (int j = 0; j < 4; ++j) {
        int f4 = t + j * 256;
        int row = f4 >> 7;
        int col = (f4 & 127) * 4;
        int rr = r0 + row;
        if (rr >= C_SZ) rr = C_SZ - 1;
        *(float4*)&ps[row][col] = *(const float4*)&new_proto[(size_t)rr * F_SZ + col];
    }
    __syncthreads();
    const int c0 = t;
    const int c1 = t + 256;
    float acc0[8] = {};
    float acc1[8] = {};
#pragma unroll 4
    for (int k = 0; k < F_SZ; ++k) {
        float w0 = W_fc[k * C_SZ + c0];
        float w1 = (c1 < C_SZ) ? W_fc[k * C_SZ + c1] : 0.0f;
#pragma unroll
        for (int r = 0; r < 8; ++r) {
            float f = ps[r][k];
            acc0[r] += f * w0;
            acc1[r] += f * w1;
        }
    }
    float bb0 = b_fc[c0];
    float bb1 = (c1 < C_SZ) ? b_fc[c1] : 0.0f;
#pragma unroll
    for (int r = 0; r < 8; ++r) {
        if (r0 + r < C_SZ) {
            scores[(size_t)(r0 + r) * C_SZ + c0] = acc0[r] + bb0;
            if (c1 < C_SZ) scores[(size_t)(r0 + r) * C_SZ + c1] = acc1[r] + bb1;
        }
    }
}

// ---------------------------------------------------------------------------
extern "C" void kernel_launch(void* const* d_in, const int* in_sizes, int n_in,
                              void* d_out, int out_size, void* d_ws, size_t ws_size,
                              hipStream_t stream)
{
    const float* img_q     = (const float*)d_in[0];
    const float* img_q1    = (const float*)d_in[1];
    const float* partial_Y = (const float*)d_in[2];
    const float* W_enc     = (const float*)d_in[3];
    const float* W_fc      = (const float*)d_in[4];
    const float* b_fc      = (const float*)d_in[5];
    const float* proto     = (const float*)d_in[6];

    float* out       = (float*)d_out;
    float* logits    = out;            // [2048][345]
    float* new_proto = out + 706560;   // [345][512]
    float* scores    = out + 883200;   // [345][345]
    float* labels_f  = out + 1002225;  // [1024]
    float* feats     = out + 1003249;  // [2048][512]

    char* ws = (char*)d_ws;
    if (ws_size >= (size_t)WS_NEED) {
        short* Xh  = (short*)(ws + WS_XH);
        short* Xl  = (short*)(ws + WS_XL);
        short* Wh  = (short*)(ws + WS_WH);
        short* Wl  = (short*)(ws + WS_WL);
        float* P   = (float*)(ws + WS_P);
        // overlay region (written only AFTER gemm_ws128 has consumed Xh/Xl)
        short* Fh  = (short*)(ws + WS_FH);
        short* Fl  = (short*)(ws + WS_FL);
        short* Wth = (short*)(ws + WS_WFH);
        short* Wtl = (short*)(ws + WS_WFL);
        short* NPh = (short*)(ws + WS_NPH);
        short* NPl = (short*)(ws + WS_NPL);

        hipLaunchKernelGGL(convert_all, dim3(2048), dim3(256), 0, stream,
                           img_q, img_q1, W_enc, Xh, Xl, Wh, Wl);
        hipLaunchKernelGGL(gemm_ws128, dim3(4, 16, 2), dim3(256), 0, stream,
                           Xh, Xl, Wh, Wl, P);
        hipLaunchKernelGGL(reduce_feats_split, dim3(1072), dim3(256), 0, stream,
                           P, feats, Fh, Fl, W_fc, Wth, Wtl);
        hipLaunchKernelGGL(gemm_fc, dim3(6, 32), dim3(256), 0, stream,
                           Fh, Fl, Wth, Wtl, b_fc, logits, 2048);
        hipLaunchKernelGGL(argmax_labels, dim3(1024), dim3(64), 0, stream,
                           logits, partial_Y, labels_f);
        hipLaunchKernelGGL(proto_update, dim3(345), dim3(512), 0, stream,
                           labels_f, feats, proto, new_proto, NPh, NPl);
        hipLaunchKernelGGL(gemm_fc, dim3(6, 6), dim3(256), 0, stream,
                           NPh, NPl, Wth, Wtl, b_fc, scores, C_SZ);
    } else {
        hipLaunchKernelGGL(gemm_enc_mfma, dim3(8, 32), dim3(256), 0, stream,
                           img_q, img_q1, W_enc, feats);
        hipLaunchKernelGGL(fc_logits_fused, dim3(512), dim3(256), 0, stream,
                           feats, W_fc, b_fc, partial_Y, logits, labels_f);
        hipLaunchKernelGGL(proto_update, dim3(345), dim3(512), 0, stream,
                           labels_f, feats, proto, new_proto, (short*)nullptr, (short*)nullptr);
        hipLaunchKernelGGL(fc_proto, dim3(44), dim3(256), 0, stream,
                           new_proto, W_fc, b_fc, scores);
    }
}

// Round 7
// 318.611 us; speedup vs baseline: 1.0506x; 1.0506x over previous
//
#include <hip/hip_runtime.h>
#include <float.h>
#include <math.h>

// Problem constants
#define B_SZ 1024
#define D_SZ 8192
#define C_SZ 345
#define F_SZ 512
#define PROTO_W 0.99f

// d_out layout (float32, flat, reference return order):
//   logits   [2048][345]  @ 0
//   new_proto[345][512]   @ 706560
//   scores   [345][345]   @ 883200
//   labels   [1024]       @ 1002225  (stored as float)
//   feats    [2048][512]  @ 1003249

// ---------------- NEW-path d_ws layout (NO overlay — no ordering hazards) ---
//   Xh  [2048][8192] bf16 @ 0
//   Xl  [2048][8192] bf16 @ 33554432
//   Wh  [512][8192]  bf16 @ 67108864   ([n][k] transposed)
//   Wl  [512][8192]  bf16 @ 75497472
//   P   [4][2048][512] f32 @ 83886080  (split-K=4 partials, 16 MB)
//   Wth [384][512]  bf16 @ 100663296  (W_fc^T, rows>=345 zero)
//   Wtl [384][512]  bf16 @ 101056512
//   labPack [1024] u64   @ 101449728  (packed argmax accumulators)
#define WS_XH 0
#define WS_XL 33554432u
#define WS_WH 67108864u
#define WS_WL 75497472u
#define WS_P  83886080u
#define WS2_WFH 100663296u
#define WS2_WFL 101056512u
#define WS2_LAB 101449728u
#define WS2_NEED 101457920u

// ---------------- OLD-path (R6 fallback) overlay offsets ---------------------
#define WS_NEED 92274688u
#define WS_FH  0u
#define WS_FL  2097152u
#define WS_WFH 4194304u
#define WS_WFL 4587520u
#define WS_NPH 4980736u
#define WS_NPL 5373952u

typedef short bf16x8 __attribute__((ext_vector_type(8)));
typedef short short4v __attribute__((ext_vector_type(4)));
typedef short short8v __attribute__((ext_vector_type(8)));
typedef float f32x4  __attribute__((ext_vector_type(4)));

__device__ __forceinline__ void split_bf16(float x, short& hi, short& lo) {
    unsigned u = __float_as_uint(x);
    unsigned r = (u + 0x7FFFu + ((u >> 16) & 1u)) >> 16;
    hi = (short)r;
    float hf = __uint_as_float(r << 16);
    lo = (short)(__float_as_uint(x - hf) >> 16);
}
__device__ __forceinline__ float bf16_f32(short h) {
    return __uint_as_float(((unsigned)(unsigned short)h) << 16);
}

__device__ __forceinline__ void gl_lds16(const short* g, short* l) {
    __builtin_amdgcn_global_load_lds(
        (const __attribute__((address_space(1))) void*)g,
        (__attribute__((address_space(3))) void*)l, 16, 0, 0);
}

// order-preserving float -> u32 key (larger float => larger key)
__device__ __forceinline__ unsigned f2key(float v) {
    unsigned u = __float_as_uint(v);
    return (u & 0x80000000u) ? ~u : (u | 0x80000000u);
}

#define MFMA_BF16 __builtin_amdgcn_mfma_f32_16x16x32_bf16

// 12-MFMA bf16x3 block (2x2 frags); expects sAh/sAl/sBh/sBl + acc in scope.
#define MFMA_BLOCK(IA0, IA1, IB0, IB1)                                   \
    do {                                                                 \
        bf16x8 a0h = *(const bf16x8*)&sAh[IA0];                          \
        bf16x8 a1h = *(const bf16x8*)&sAh[IA1];                          \
        bf16x8 b0h = *(const bf16x8*)&sBh[IB0];                          \
        bf16x8 b1h = *(const bf16x8*)&sBh[IB1];                          \
        bf16x8 a0l = *(const bf16x8*)&sAl[IA0];                          \
        bf16x8 a1l = *(const bf16x8*)&sAl[IA1];                          \
        bf16x8 b0l = *(const bf16x8*)&sBl[IB0];                          \
        bf16x8 b1l = *(const bf16x8*)&sBl[IB1];                          \
        acc[0][0] = MFMA_BF16(a0h, b0h, acc[0][0], 0, 0, 0);             \
        acc[0][1] = MFMA_BF16(a0h, b1h, acc[0][1], 0, 0, 0);             \
        acc[1][0] = MFMA_BF16(a1h, b0h, acc[1][0], 0, 0, 0);             \
        acc[1][1] = MFMA_BF16(a1h, b1h, acc[1][1], 0, 0, 0);             \
        acc[0][0] = MFMA_BF16(a0h, b0l, acc[0][0], 0, 0, 0);             \
        acc[0][1] = MFMA_BF16(a0h, b1l, acc[0][1], 0, 0, 0);             \
        acc[1][0] = MFMA_BF16(a1h, b0l, acc[1][0], 0, 0, 0);             \
        acc[1][1] = MFMA_BF16(a1h, b1l, acc[1][1], 0, 0, 0);             \
        acc[0][0] = MFMA_BF16(a0l, b0h, acc[0][0], 0, 0, 0);             \
        acc[0][1] = MFMA_BF16(a0l, b1h, acc[0][1], 0, 0, 0);             \
        acc[1][0] = MFMA_BF16(a1l, b0h, acc[1][0], 0, 0, 0);             \
        acc[1][1] = MFMA_BF16(a1l, b1h, acc[1][1], 0, 0, 0);             \
    } while (0)

// ---------------------------------------------------------------------------
// convert_all:
//   blocks [0,1024):    X fp32 -> Xh/Xl
//   blocks [1024,2048): W_enc [k][n] -> Wh/Wl [n][k]
//   blocks [2048,2096): W_fc [k][c] -> Wth/Wtl [c][k] (only launched new-path;
//                       Wth/Wtl live OUTSIDE the gemm inputs -> no hazard)
// ---------------------------------------------------------------------------
__global__ __launch_bounds__(256) void convert_all(
    const float* __restrict__ img_q, const float* __restrict__ img_q1,
    const float* __restrict__ W_enc, const float* __restrict__ W_fc,
    short* __restrict__ Xh, short* __restrict__ Xl,
    short* __restrict__ Wh, short* __restrict__ Wl,
    short* __restrict__ Wth, short* __restrict__ Wtl)
{
    __shared__ float tile[64][65];
    const int bid = blockIdx.x;
    const int t = threadIdx.x;

    if (bid < 1024) {
        const int HALF = (B_SZ * D_SZ) / 4;
        const int total = 2 * HALF;
        for (int i4 = bid * 256 + t; i4 < total; i4 += 1024 * 256) {
            float4 v = (i4 < HALF) ? ((const float4*)img_q)[i4]
                                   : ((const float4*)img_q1)[i4 - HALF];
            short4v h, l;
            short hh, ll;
            split_bf16(v.x, hh, ll); h.x = hh; l.x = ll;
            split_bf16(v.y, hh, ll); h.y = hh; l.y = ll;
            split_bf16(v.z, hh, ll); h.z = hh; l.z = ll;
            split_bf16(v.w, hh, ll); h.w = hh; l.w = ll;
            ((short4v*)Xh)[i4] = h;
            ((short4v*)Xl)[i4] = l;
        }
    } else if (bid < 2048) {
        const int id = bid - 1024;
        const int k0 = (id >> 3) * 64;
        const int n0 = (id & 7) * 64;
        {
            const int kr = t >> 2;
            const int cb = (t & 3) * 16;
#pragma unroll
            for (int j = 0; j < 4; ++j) {
                float4 v = *(const float4*)&W_enc[(size_t)(k0 + kr) * F_SZ + n0 + cb + j * 4];
                tile[kr][cb + j * 4 + 0] = v.x;
                tile[kr][cb + j * 4 + 1] = v.y;
                tile[kr][cb + j * 4 + 2] = v.z;
                tile[kr][cb + j * 4 + 3] = v.w;
            }
        }
        __syncthreads();
        const int n = t >> 2;
#pragma unroll
        for (int cc = 0; cc < 2; ++cc) {
            const int ch = (t & 3) * 2 + cc;
            short8v h, l;
#pragma unroll
            for (int e = 0; e < 8; ++e) {
                short hh, ll;
                split_bf16(tile[ch * 8 + e][n], hh, ll);
                h[e] = hh; l[e] = ll;
            }
            size_t off = (size_t)(n0 + n) * D_SZ + k0 + ch * 8;
            *(short8v*)&Wh[off] = h;
            *(short8v*)&Wl[off] = l;
        }
    } else {
        const int id = bid - 2048;
        const int k0 = (id & 7) * 64;
        const int c0 = (id >> 3) * 64;
        for (int idx = t; idx < 64 * 64; idx += 256) {
            const int kr = idx >> 6;
            const int cc = idx & 63;
            tile[kr][cc] = (c0 + cc < C_SZ) ? W_fc[(size_t)(k0 + kr) * C_SZ + c0 + cc] : 0.0f;
        }
        __syncthreads();
        const int crow = t >> 2;
#pragma unroll
        for (int cc2 = 0; cc2 < 2; ++cc2) {
            const int ch = (t & 3) * 2 + cc2;
            short8v h, l;
#pragma unroll
            for (int e = 0; e < 8; ++e) {
                short hh, ll;
                split_bf16(tile[ch * 8 + e][crow], hh, ll);
                h[e] = hh; l[e] = ll;
            }
            size_t off = (size_t)(c0 + crow) * F_SZ + k0 + ch * 8;
            *(short8v*)&Wth[off] = h;
            *(short8v*)&Wtl[off] = l;
        }
    }
}

// ---------------------------------------------------------------------------
// gemm_ws128: P[ks] = A(128 x ksteps*64) @ B(.. x 128), bf16x3, split-K via
// blockIdx.z. 128x128 tile, 4 waves (64x64 quadrant, 4x4 frags), double-
// buffered LDS (128 KB), gl_lds staging, XOR-swizzled (0 conflicts measured).
// New path: grid (4,16,4), ksteps=32 -> full 256-CU coverage.
// ---------------------------------------------------------------------------
__global__ __launch_bounds__(256, 1) void gemm_ws128(
    const short* __restrict__ Xh, const short* __restrict__ Xl,
    const short* __restrict__ Wh, const short* __restrict__ Wl,
    float* __restrict__ P, int ksteps)
{
    __shared__ __align__(16) short sAh[2][8192];
    __shared__ __align__(16) short sAl[2][8192];
    __shared__ __align__(16) short sBh[2][8192];
    __shared__ __align__(16) short sBl[2][8192];

    const int t = threadIdx.x;
    const int lane = t & 63;
    const int wave = t >> 6;
    const int nt = blockIdx.x;
    const int mt = blockIdx.y;
    const int ks = blockIdx.z;
    const int m0 = mt * 128;
    const int n0 = nt * 128;
    const int kbase = ks * ksteps * 64;

    const short* gbase =
        (wave == 0) ? Xh + (size_t)m0 * D_SZ :
        (wave == 1) ? Xl + (size_t)m0 * D_SZ :
        (wave == 2) ? Wh + (size_t)n0 * D_SZ :
                      Wl + (size_t)n0 * D_SZ;
    short* lb[2];
    lb[0] = (wave == 0) ? sAh[0] : (wave == 1) ? sAl[0] : (wave == 2) ? sBh[0] : sBl[0];
    lb[1] = (wave == 0) ? sAh[1] : (wave == 1) ? sAl[1] : (wave == 2) ? sBh[1] : sBl[1];
    const int lrow8 = lane >> 3;
    const int gchunkOff = ((lane & 7) ^ lrow8) * 8;
    const short* gsrc = gbase + (size_t)lrow8 * D_SZ + kbase + gchunkOff;

    const int mo = (wave >> 1) * 64;
    const int no = (wave & 1) * 64;
    const int lr = lane & 15;
    const int lkg = lane >> 4;
    const int x7 = lr & 7;
    const int sl0 = lkg ^ x7;
    const int sl1 = (4 + lkg) ^ x7;
    int aoff[4], boff[4];
#pragma unroll
    for (int f = 0; f < 4; ++f) {
        aoff[f] = (mo + 16 * f + lr) * 64;
        boff[f] = (no + 16 * f + lr) * 64;
    }

    f32x4 acc[4][4] = {};

#pragma unroll
    for (int j = 0; j < 16; ++j)
        gl_lds16(gsrc + (size_t)(8 * j) * D_SZ, lb[0] + j * 512);
    __syncthreads();

    int buf = 0;
    for (int s = 0; s < ksteps; ++s) {
        if (s + 1 < ksteps) {
            short* dst = lb[buf ^ 1];
            const short* g = gsrc + (s + 1) * 64;
#pragma unroll
            for (int j = 0; j < 16; ++j)
                gl_lds16(g + (size_t)(8 * j) * D_SZ, dst + j * 512);
        }
        const short* pAh = sAh[buf];
        const short* pAl = sAl[buf];
        const short* pBh = sBh[buf];
        const short* pBl = sBl[buf];
#pragma unroll
        for (int ksub = 0; ksub < 2; ++ksub) {
            const int sl = ksub ? sl1 : sl0;
            bf16x8 ah[4], al[4], bh[4], blo[4];
#pragma unroll
            for (int f = 0; f < 4; ++f) {
                ah[f]  = *(const bf16x8*)&pAh[aoff[f] + sl * 8];
                al[f]  = *(const bf16x8*)&pAl[aoff[f] + sl * 8];
            }
#pragma unroll
            for (int g = 0; g < 4; ++g) {
                bh[g]  = *(const bf16x8*)&pBh[boff[g] + sl * 8];
                blo[g] = *(const bf16x8*)&pBl[boff[g] + sl * 8];
            }
#pragma unroll
            for (int f = 0; f < 4; ++f)
#pragma unroll
                for (int g = 0; g < 4; ++g)
                    acc[f][g] = MFMA_BF16(ah[f], bh[g], acc[f][g], 0, 0, 0);
#pragma unroll
            for (int f = 0; f < 4; ++f)
#pragma unroll
                for (int g = 0; g < 4; ++g)
                    acc[f][g] = MFMA_BF16(ah[f], blo[g], acc[f][g], 0, 0, 0);
#pragma unroll
            for (int f = 0; f < 4; ++f)
#pragma unroll
                for (int g = 0; g < 4; ++g)
                    acc[f][g] = MFMA_BF16(al[f], bh[g], acc[f][g], 0, 0, 0);
        }
        __syncthreads();
        buf ^= 1;
    }

    float* Pout = P + (size_t)ks * (2048u * 512u);
#pragma unroll
    for (int f = 0; f < 4; ++f)
#pragma unroll
        for (int g = 0; g < 4; ++g) {
            const int col  = n0 + no + 16 * g + (lane & 15);
            const int row0 = m0 + mo + 16 * f + (lane >> 4) * 4;
#pragma unroll
            for (int r = 0; r < 4; ++r)
                Pout[(size_t)(row0 + r) * F_SZ + col] = acc[f][g][r];
        }
}

// ---------------------------------------------------------------------------
// fc_logits_fused2 (NEW path): per 64x64 output tile of logits:
//   A-tile = sum of 4 P slices, summed+split to bf16 hi/lo in-kernel (no
//   global Fh/Fl round trip); nt==0 blocks also emit fp32 feats.
//   B from Wth/Wtl via global_load_lds. bf16x3 MFMA. Epilogue: +bias, store
//   logits, and for rows<1024 masked argmax via packed atomicMax -> labPack.
// grid (6, 32), 256 threads.
// ---------------------------------------------------------------------------
__global__ __launch_bounds__(256) void fc_logits_fused2(
    const float* __restrict__ P,
    const short* __restrict__ Bh_g, const short* __restrict__ Bl_g,
    const float* __restrict__ bias, const float* __restrict__ partial_Y,
    float* __restrict__ logits, float* __restrict__ feats,
    unsigned long long* __restrict__ labPack)
{
    __shared__ __align__(16) short sAh[4096];
    __shared__ __align__(16) short sAl[4096];
    __shared__ __align__(16) short sBh[4096];
    __shared__ __align__(16) short sBl[4096];

    const int t = threadIdx.x;
    const int lane = t & 63;
    const int wave = t >> 6;
    const int n0 = blockIdx.x * 64;
    const int m0 = blockIdx.y * 64;
    const bool writeF = (blockIdx.x == 0);

    const int lrow8 = lane >> 3;
    const int colOff = ((lane & 7) ^ lrow8) * 8;

    const int mo = (wave >> 1) * 32;
    const int no = (wave & 1) * 32;
    const int lr = lane & 15;
    const int lkg = lane >> 4;
    const int x7 = lr & 7;
    const int sl0 = (0 + lkg) ^ x7;
    const int sl1 = (4 + lkg) ^ x7;
    const int ra0 = (mo + lr) * 64,      ra1 = (mo + 16 + lr) * 64;
    const int rb0 = (no + lr) * 64,      rb1 = (no + 16 + lr) * 64;
    const int a00 = ra0 + sl0 * 8, a01 = ra0 + sl1 * 8;
    const int a10 = ra1 + sl0 * 8, a11 = ra1 + sl1 * 8;
    const int b00 = rb0 + sl0 * 8, b01 = rb0 + sl1 * 8;
    const int b10 = rb1 + sl0 * 8, b11 = rb1 + sl1 * 8;

    f32x4 acc[2][2] = {};

    for (int s = 0; s < 8; ++s) {
        __syncthreads();
        // B staging: wave0 -> sBh, wave1 -> sBl (rows < 384 allocated)
        if (wave < 2) {
            const short* gB = (wave == 0) ? Bh_g : Bl_g;
            short* lbase = (wave == 0) ? sBh : sBl;
#pragma unroll
            for (int j = 0; j < 8; ++j) {
                int row = n0 + lrow8 + 8 * j;
                gl_lds16(gB + (size_t)row * F_SZ + s * 64 + colOff, lbase + j * 512);
            }
        }
        // A staging: all threads; chunk q -> (row=q>>3, c=q&7), 8 fp32 each
#pragma unroll
        for (int qq = 0; qq < 2; ++qq) {
            const int q = t + qq * 256;
            const int row = q >> 3;
            const int c = q & 7;
            const size_t gidx = (size_t)(m0 + row) * F_SZ + s * 64 + c * 8;
            float4 v0 = ((const float4*)&P[gidx])[0];
            float4 v1 = ((const float4*)&P[gidx])[1];
#pragma unroll
            for (int sl = 1; sl < 4; ++sl) {
                const float* Ps = P + (size_t)sl * (2048u * 512u);
                float4 u0 = ((const float4*)&Ps[gidx])[0];
                float4 u1 = ((const float4*)&Ps[gidx])[1];
                v0.x += u0.x; v0.y += u0.y; v0.z += u0.z; v0.w += u0.w;
                v1.x += u1.x; v1.y += u1.y; v1.z += u1.z; v1.w += u1.w;
            }
            float f[8] = {v0.x, v0.y, v0.z, v0.w, v1.x, v1.y, v1.z, v1.w};
            if (writeF) {
#pragma unroll
                for (int e = 0; e < 8; ++e) feats[gidx + e] = f[e];
            }
            bf16x8 h, l;
#pragma unroll
            for (int e = 0; e < 8; ++e) { short hh, ll; split_bf16(f[e], hh, ll); h[e] = hh; l[e] = ll; }
            const int slot = c ^ (row & 7);
            *(bf16x8*)&sAh[row * 64 + slot * 8] = h;
            *(bf16x8*)&sAl[row * 64 + slot * 8] = l;
        }
        __syncthreads();
        MFMA_BLOCK(a00, a10, b00, b10);
        MFMA_BLOCK(a01, a11, b01, b11);
    }

    // epilogue: bias + store logits (+ masked argmax for rows < 1024)
    const bool doArg = (m0 < B_SZ);
#pragma unroll
    for (int f = 0; f < 2; ++f) {
#pragma unroll
        for (int r = 0; r < 4; ++r) {
            const int row = m0 + mo + f * 16 + (lane >> 4) * 4 + r;
            unsigned long long best = 0;   // identity for atomicMax
#pragma unroll
            for (int g = 0; g < 2; ++g) {
                const int col = n0 + no + g * 16 + (lane & 15);
                if (col < C_SZ) {
                    const float v = acc[f][g][r] + bias[col];
                    logits[(size_t)row * C_SZ + col] = v;
                    if (doArg && partial_Y[(size_t)row * C_SZ + col] != 0.0f) {
                        unsigned long long p = ((unsigned long long)f2key(v) << 32)
                                             | (unsigned long long)(0xFFFFFFFFu - (unsigned)col);
                        if (p > best) best = p;
                    }
                }
            }
            if (doArg) {
                // reduce across the 16-lane group holding this row
#pragma unroll
                for (int m = 1; m < 16; m <<= 1) {
                    unsigned long long o = __shfl_xor(best, m);
                    if (o > best) best = o;
                }
                if ((lane & 15) == 0 && best != 0)
                    atomicMax(&labPack[row], best);
            }
        }
    }
}

// ---------------------------------------------------------------------------
// proto_scores_fused (NEW path): decode labels from labPack (block 0 writes
// labels_f), sequential EMA per class from feats, L2 renorm, write new_proto,
// then compute this class's scores row: b_fc + NP_c . (Wth+Wtl) in fp32.
// grid 345, 512 threads.
// ---------------------------------------------------------------------------
__global__ __launch_bounds__(512) void proto_scores_fused(
    const unsigned long long* __restrict__ labPack,
    const float* __restrict__ feats_q,
    const float* __restrict__ proto,
    const short* __restrict__ Wth, const short* __restrict__ Wtl,
    const float* __restrict__ b_fc,
    float* __restrict__ new_proto, float* __restrict__ scores,
    float* __restrict__ labels_f)
{
    __shared__ int lab[B_SZ];
    __shared__ float nprow[F_SZ];
    __shared__ float red[8];
    __shared__ float rinv_s;
    const int c = blockIdx.x;
    const int t = threadIdx.x;
    for (int i = t; i < B_SZ; i += 512) {
        int li = (int)(0xFFFFFFFFu - (unsigned)(labPack[i] & 0xFFFFFFFFull));
        lab[i] = li;
        if (c == 0) labels_f[i] = (float)li;
    }
    __syncthreads();
    float val = proto[(size_t)c * F_SZ + t];
    for (int i = 0; i < B_SZ; ++i) {
        if (lab[i] == c)
            val = PROTO_W * val + (1.0f - PROTO_W) * feats_q[(size_t)i * F_SZ + t];
    }
    float sq = val * val;
#pragma unroll
    for (int off = 32; off; off >>= 1) sq += __shfl_down(sq, off);
    if ((t & 63) == 0) red[t >> 6] = sq;
    __syncthreads();
    if (t == 0) {
        float s = 0.0f;
#pragma unroll
        for (int w = 0; w < 8; ++w) s += red[w];
        rinv_s = 1.0f / sqrtf(s);
    }
    __syncthreads();
    const float v = val * rinv_s;
    new_proto[(size_t)c * F_SZ + t] = v;
    nprow[t] = v;
    __syncthreads();
    if (t < C_SZ) {
        float acc = b_fc[t];
        const short* wh = Wth + (size_t)t * F_SZ;
        const short* wl = Wtl + (size_t)t * F_SZ;
        for (int k = 0; k < F_SZ; k += 8) {
            short8v h = *(const short8v*)&wh[k];
            short8v l = *(const short8v*)&wl[k];
#pragma unroll
            for (int e = 0; e < 8; ++e)
                acc += nprow[k + e] * (bf16_f32(h[e]) + bf16_f32(l[e]));
        }
        scores[(size_t)c * C_SZ + t] = acc;
    }
}

// ===========================================================================
// OLD-path kernels (R6-proven fallback; used when ws < WS2_NEED)
// ===========================================================================
__global__ __launch_bounds__(256) void reduce_feats_split(
    const float* __restrict__ P, float* __restrict__ feats,
    short* __restrict__ Fh, short* __restrict__ Fl,
    const float* __restrict__ W_fc,
    short* __restrict__ Wth, short* __restrict__ Wtl)
{
    const int bid = blockIdx.x;
    const int t = threadIdx.x;
    if (bid < 1024) {
        const int n4 = (2048 * 512) / 4;
        const float* P1 = P + 2048 * 512;
        for (int i4 = bid * 256 + t; i4 < n4; i4 += 1024 * 256) {
            float4 a = ((const float4*)P)[i4];
            float4 b = ((const float4*)P1)[i4];
            float v[4] = {a.x + b.x, a.y + b.y, a.z + b.z, a.w + b.w};
            short4v h, l;
            short hh, ll;
#pragma unroll
            for (int e = 0; e < 4; ++e) {
                feats[i4 * 4 + e] = v[e];
                split_bf16(v[e], hh, ll); h[e] = hh; l[e] = ll;
            }
            ((short4v*)Fh)[i4] = h;
            ((short4v*)Fl)[i4] = l;
        }
    } else {
        __shared__ float tile[64][65];
        const int id = bid - 1024;
        const int k0 = (id & 7) * 64;
        const int c0 = (id >> 3) * 64;
        for (int idx = t; idx < 64 * 64; idx += 256) {
            const int kr = idx >> 6;
            const int cc = idx & 63;
            tile[kr][cc] = (c0 + cc < C_SZ) ? W_fc[(size_t)(k0 + kr) * C_SZ + c0 + cc] : 0.0f;
        }
        __syncthreads();
        const int crow = t >> 2;
#pragma unroll
        for (int cc2 = 0; cc2 < 2; ++cc2) {
            const int ch = (t & 3) * 2 + cc2;
            short8v h, l;
#pragma unroll
            for (int e = 0; e < 8; ++e) {
                short hh, ll;
                split_bf16(tile[ch * 8 + e][crow], hh, ll);
                h[e] = hh; l[e] = ll;
            }
            size_t off = (size_t)(c0 + crow) * F_SZ + k0 + ch * 8;
            *(short8v*)&Wth[off] = h;
            *(short8v*)&Wtl[off] = l;
        }
    }
}

__global__ __launch_bounds__(256) void gemm_fc(
    const short* __restrict__ Ah, const short* __restrict__ Al,
    const short* __restrict__ Bh, const short* __restrict__ Bl,
    const float* __restrict__ bias, float* __restrict__ Cout, int M)
{
    __shared__ __align__(16) short sAh[4096];
    __shared__ __align__(16) short sAl[4096];
    __shared__ __align__(16) short sBh[4096];
    __shared__ __align__(16) short sBl[4096];

    const int t = threadIdx.x;
    const int lane = t & 63;
    const int wave = t >> 6;
    const int n0 = blockIdx.x * 64;
    const int m0 = blockIdx.y * 64;

    const int lrow8 = lane >> 3;
    const int colOff = ((lane & 7) ^ lrow8) * 8;

    short* lbase = (wave == 0) ? sAh : (wave == 1) ? sAl : (wave == 2) ? sBh : sBl;
    const short* gA = (wave == 1) ? Al : Ah;
    const short* gB = (wave == 3) ? Bl : Bh;
    const bool isA = wave < 2;

    const int mo = (wave >> 1) * 32;
    const int no = (wave & 1) * 32;
    const int lr = lane & 15;
    const int lkg = lane >> 4;
    const int x7 = lr & 7;
    const int sl0 = (0 + lkg) ^ x7;
    const int sl1 = (4 + lkg) ^ x7;
    const int ra0 = (mo + lr) * 64,      ra1 = (mo + 16 + lr) * 64;
    const int rb0 = (no + lr) * 64,      rb1 = (no + 16 + lr) * 64;
    const int a00 = ra0 + sl0 * 8, a01 = ra0 + sl1 * 8;
    const int a10 = ra1 + sl0 * 8, a11 = ra1 + sl1 * 8;
    const int b00 = rb0 + sl0 * 8, b01 = rb0 + sl1 * 8;
    const int b10 = rb1 + sl0 * 8, b11 = rb1 + sl1 * 8;

    f32x4 acc[2][2] = {};

    for (int s = 0; s < 8; ++s) {
        __syncthreads();
        if (isA) {
#pragma unroll
            for (int j = 0; j < 8; ++j) {
                int row = m0 + lrow8 + 8 * j;
                if (row > M - 1) row = M - 1;
                gl_lds16(gA + (size_t)row * F_SZ + s * 64 + colOff, lbase + j * 512);
            }
        } else {
#pragma unroll
            for (int j = 0; j < 8; ++j) {
                int row = n0 + lrow8 + 8 * j;
                gl_lds16(gB + (size_t)row * F_SZ + s * 64 + colOff, lbase + j * 512);
            }
        }
        __syncthreads();
        MFMA_BLOCK(a00, a10, b00, b10);
        MFMA_BLOCK(a01, a11, b01, b11);
    }

#pragma unroll
    for (int f = 0; f < 2; ++f)
#pragma unroll
        for (int g = 0; g < 2; ++g) {
            const int col  = n0 + no + g * 16 + (lane & 15);
            if (col >= C_SZ) continue;
            const float bb = bias[col];
            const int row0 = m0 + mo + f * 16 + (lane >> 4) * 4;
#pragma unroll
            for (int r = 0; r < 4; ++r) {
                const int row = row0 + r;
                if (row < M)
                    Cout[(size_t)row * C_SZ + col] = acc[f][g][r] + bb;
            }
        }
}

__global__ __launch_bounds__(64) void argmax_labels(
    const float* __restrict__ logits, const float* __restrict__ partial_Y,
    float* __restrict__ labels_f)
{
    const int i = blockIdx.x;
    const int lane = threadIdx.x;
    float best = -FLT_MAX;
    int bidx = C_SZ;
    for (int c = lane; c < C_SZ; c += 64) {
        if (partial_Y[(size_t)i * C_SZ + c] != 0.0f) {
            float v = logits[(size_t)i * C_SZ + c];
            if (v > best || (v == best && c < bidx)) { best = v; bidx = c; }
        }
    }
#pragma unroll
    for (int off = 32; off; off >>= 1) {
        float ov = __shfl_down(best, off);
        int oi = __shfl_down(bidx, off);
        if (ov > best || (ov == best && oi < bidx)) { best = ov; bidx = oi; }
    }
    if (lane == 0) labels_f[i] = (float)bidx;
}

__global__ __launch_bounds__(512) void proto_update(
    const float* __restrict__ labels_f, const float* __restrict__ feats_q,
    const float* __restrict__ proto, float* __restrict__ new_proto,
    short* __restrict__ NPh, short* __restrict__ NPl)
{
    __shared__ int lab[B_SZ];
    __shared__ float red[8];
    __shared__ float rinv_s;
    const int c = blockIdx.x;
    const int t = threadIdx.x;
    for (int i = t; i < B_SZ; i += 512) lab[i] = (int)labels_f[i];
    __syncthreads();
    float val = proto[(size_t)c * F_SZ + t];
    for (int i = 0; i < B_SZ; ++i) {
        if (lab[i] == c)
            val = PROTO_W * val + (1.0f - PROTO_W) * feats_q[(size_t)i * F_SZ + t];
    }
    float sq = val * val;
#pragma unroll
    for (int off = 32; off; off >>= 1) sq += __shfl_down(sq, off);
    if ((t & 63) == 0) red[t >> 6] = sq;
    __syncthreads();
    if (t == 0) {
        float s = 0.0f;
#pragma unroll
        for (int w = 0; w < 8; ++w) s += red[w];
        rinv_s = 1.0f / sqrtf(s);
    }
    __syncthreads();
    const float v = val * rinv_s;
    new_proto[(size_t)c * F_SZ + t] = v;
    if (NPh) {
        short hh, ll;
        split_bf16(v, hh, ll);
        NPh[(size_t)c * F_SZ + t] = hh;
        NPl[(size_t)c * F_SZ + t] = ll;
    }
}

// ---------------------------------------------------------------------------
extern "C" void kernel_launch(void* const* d_in, const int* in_sizes, int n_in,
                              void* d_out, int out_size, void* d_ws, size_t ws_size,
                              hipStream_t stream)
{
    const float* img_q     = (const float*)d_in[0];
    const float* img_q1    = (const float*)d_in[1];
    const float* partial_Y = (const float*)d_in[2];
    const float* W_enc     = (const float*)d_in[3];
    const float* W_fc      = (const float*)d_in[4];
    const float* b_fc      = (const float*)d_in[5];
    const float* proto     = (const float*)d_in[6];

    float* out       = (float*)d_out;
    float* logits    = out;            // [2048][345]
    float* new_proto = out + 706560;   // [345][512]
    float* scores    = out + 883200;   // [345][345]
    float* labels_f  = out + 1002225;  // [1024]
    float* feats     = out + 1003249;  // [2048][512]

    char* ws = (char*)d_ws;
    short* Xh = (short*)(ws + WS_XH);
    short* Xl = (short*)(ws + WS_XL);
    short* Wh = (short*)(ws + WS_WH);
    short* Wl = (short*)(ws + WS_WL);
    float* P  = (float*)(ws + WS_P);

    if (ws_size >= (size_t)WS2_NEED) {
        // ---------------- NEW path: 5 nodes, no overlay ----------------
        short* Wth = (short*)(ws + WS2_WFH);
        short* Wtl = (short*)(ws + WS2_WFL);
        unsigned long long* labPack = (unsigned long long*)(ws + WS2_LAB);

        hipMemsetAsync(labPack, 0, B_SZ * sizeof(unsigned long long), stream);
        hipLaunchKernelGGL(convert_all, dim3(2096), dim3(256), 0, stream,
                           img_q, img_q1, W_enc, W_fc, Xh, Xl, Wh, Wl, Wth, Wtl);
        hipLaunchKernelGGL(gemm_ws128, dim3(4, 16, 4), dim3(256), 0, stream,
                           Xh, Xl, Wh, Wl, P, 32);
        hipLaunchKernelGGL(fc_logits_fused2, dim3(6, 32), dim3(256), 0, stream,
                           P, Wth, Wtl, b_fc, partial_Y, logits, feats, labPack);
        hipLaunchKernelGGL(proto_scores_fused, dim3(345), dim3(512), 0, stream,
                           labPack, feats, proto, Wth, Wtl, b_fc,
                           new_proto, scores, labels_f);
    } else {
        // ---------------- OLD path (R6-proven): split-K=2 + overlay ----
        short* Fh  = (short*)(ws + WS_FH);
        short* Fl  = (short*)(ws + WS_FL);
        short* Wth = (short*)(ws + WS_WFH);
        short* Wtl = (short*)(ws + WS_WFL);
        short* NPh = (short*)(ws + WS_NPH);
        short* NPl = (short*)(ws + WS_NPL);

        hipLaunchKernelGGL(convert_all, dim3(2048), dim3(256), 0, stream,
                           img_q, img_q1, W_enc, W_fc, Xh, Xl, Wh, Wl,
                           (short*)nullptr, (short*)nullptr);
        hipLaunchKernelGGL(gemm_ws128, dim3(4, 16, 2), dim3(256), 0, stream,
                           Xh, Xl, Wh, Wl, P, 64);
        hipLaunchKernelGGL(reduce_feats_split, dim3(1072), dim3(256), 0, stream,
                           P, feats, Fh, Fl, W_fc, Wth, Wtl);
        hipLaunchKernelGGL(gemm_fc, dim3(6, 32), dim3(256), 0, stream,
                           Fh, Fl, Wth, Wtl, b_fc, logits, 2048);
        hipLaunchKernelGGL(argmax_labels, dim3(1024), dim3(64), 0, stream,
                           logits, partial_Y, labels_f);
        hipLaunchKernelGGL(proto_update, dim3(345), dim3(512), 0, stream,
                           labels_f, feats, proto, new_proto, NPh, NPl);
        hipLaunchKernelGGL(gemm_fc, dim3(6, 6), dim3(256), 0, stream,
                           NPh, NPl, Wth, Wtl, b_fc, scores, C_SZ);
    }
}

// Round 8
// 260.303 us; speedup vs baseline: 1.2860x; 1.2240x over previous
//
#include <hip/hip_runtime.h>
#include <float.h>
#include <math.h>

// Problem constants
#define B_SZ 1024
#define D_SZ 8192
#define C_SZ 345
#define F_SZ 512
#define PROTO_W 0.99f

// d_out layout (float32, flat, reference return order):
//   logits   [2048][345]  @ 0
//   new_proto[345][512]   @ 706560
//   scores   [345][345]   @ 883200
//   labels   [1024]       @ 1002225  (stored as float)
//   feats    [2048][512]  @ 1003249

// ---------------- NEW-path d_ws layout (NO overlay — no ordering hazards) ---
#define WS_XH 0
#define WS_XL 33554432u
#define WS_WH 67108864u
#define WS_WL 75497472u
#define WS_P  83886080u
#define WS2_WFH 100663296u
#define WS2_WFL 101056512u
#define WS2_LAB 101449728u
#define WS2_NEED 101457920u

// ---------------- OLD-path (R6 fallback) overlay offsets ---------------------
#define WS_NEED 92274688u
#define WS_FH  0u
#define WS_FL  2097152u
#define WS_WFH 4194304u
#define WS_WFL 4587520u
#define WS_NPH 4980736u
#define WS_NPL 5373952u

typedef short bf16x8 __attribute__((ext_vector_type(8)));
typedef short short4v __attribute__((ext_vector_type(4)));
typedef short short8v __attribute__((ext_vector_type(8)));
typedef float f32x4  __attribute__((ext_vector_type(4)));

__device__ __forceinline__ void split_bf16(float x, short& hi, short& lo) {
    unsigned u = __float_as_uint(x);
    unsigned r = (u + 0x7FFFu + ((u >> 16) & 1u)) >> 16;
    hi = (short)r;
    float hf = __uint_as_float(r << 16);
    lo = (short)(__float_as_uint(x - hf) >> 16);
}
__device__ __forceinline__ float bf16_f32(short h) {
    return __uint_as_float(((unsigned)(unsigned short)h) << 16);
}

__device__ __forceinline__ void gl_lds16(const short* g, short* l) {
    __builtin_amdgcn_global_load_lds(
        (const __attribute__((address_space(1))) void*)g,
        (__attribute__((address_space(3))) void*)l, 16, 0, 0);
}

// order-preserving float -> u32 key (larger float => larger key)
__device__ __forceinline__ unsigned f2key(float v) {
    unsigned u = __float_as_uint(v);
    return (u & 0x80000000u) ? ~u : (u | 0x80000000u);
}

#define MFMA_BF16 __builtin_amdgcn_mfma_f32_16x16x32_bf16

// 12-MFMA bf16x3 block (2x2 frags); expects sAh/sAl/sBh/sBl + acc in scope.
#define MFMA_BLOCK(IA0, IA1, IB0, IB1)                                   \
    do {                                                                 \
        bf16x8 a0h = *(const bf16x8*)&sAh[IA0];                          \
        bf16x8 a1h = *(const bf16x8*)&sAh[IA1];                          \
        bf16x8 b0h = *(const bf16x8*)&sBh[IB0];                          \
        bf16x8 b1h = *(const bf16x8*)&sBh[IB1];                          \
        bf16x8 a0l = *(const bf16x8*)&sAl[IA0];                          \
        bf16x8 a1l = *(const bf16x8*)&sAl[IA1];                          \
        bf16x8 b0l = *(const bf16x8*)&sBl[IB0];                          \
        bf16x8 b1l = *(const bf16x8*)&sBl[IB1];                          \
        acc[0][0] = MFMA_BF16(a0h, b0h, acc[0][0], 0, 0, 0);             \
        acc[0][1] = MFMA_BF16(a0h, b1h, acc[0][1], 0, 0, 0);             \
        acc[1][0] = MFMA_BF16(a1h, b0h, acc[1][0], 0, 0, 0);             \
        acc[1][1] = MFMA_BF16(a1h, b1h, acc[1][1], 0, 0, 0);             \
        acc[0][0] = MFMA_BF16(a0h, b0l, acc[0][0], 0, 0, 0);             \
        acc[0][1] = MFMA_BF16(a0h, b1l, acc[0][1], 0, 0, 0);             \
        acc[1][0] = MFMA_BF16(a1h, b0l, acc[1][0], 0, 0, 0);             \
        acc[1][1] = MFMA_BF16(a1h, b1l, acc[1][1], 0, 0, 0);             \
        acc[0][0] = MFMA_BF16(a0l, b0h, acc[0][0], 0, 0, 0);             \
        acc[0][1] = MFMA_BF16(a0l, b1h, acc[0][1], 0, 0, 0);             \
        acc[1][0] = MFMA_BF16(a1l, b0h, acc[1][0], 0, 0, 0);             \
        acc[1][1] = MFMA_BF16(a1l, b1h, acc[1][1], 0, 0, 0);             \
    } while (0)

// ---------------------------------------------------------------------------
// convert_all: X -> Xh/Xl; W_enc -> Wh/Wl [n][k]; (new path) W_fc -> Wth/Wtl.
// ---------------------------------------------------------------------------
__global__ __launch_bounds__(256) void convert_all(
    const float* __restrict__ img_q, const float* __restrict__ img_q1,
    const float* __restrict__ W_enc, const float* __restrict__ W_fc,
    short* __restrict__ Xh, short* __restrict__ Xl,
    short* __restrict__ Wh, short* __restrict__ Wl,
    short* __restrict__ Wth, short* __restrict__ Wtl)
{
    __shared__ float tile[64][65];
    const int bid = blockIdx.x;
    const int t = threadIdx.x;

    if (bid < 1024) {
        const int HALF = (B_SZ * D_SZ) / 4;
        const int total = 2 * HALF;
        for (int i4 = bid * 256 + t; i4 < total; i4 += 1024 * 256) {
            float4 v = (i4 < HALF) ? ((const float4*)img_q)[i4]
                                   : ((const float4*)img_q1)[i4 - HALF];
            short4v h, l;
            short hh, ll;
            split_bf16(v.x, hh, ll); h.x = hh; l.x = ll;
            split_bf16(v.y, hh, ll); h.y = hh; l.y = ll;
            split_bf16(v.z, hh, ll); h.z = hh; l.z = ll;
            split_bf16(v.w, hh, ll); h.w = hh; l.w = ll;
            ((short4v*)Xh)[i4] = h;
            ((short4v*)Xl)[i4] = l;
        }
    } else if (bid < 2048) {
        const int id = bid - 1024;
        const int k0 = (id >> 3) * 64;
        const int n0 = (id & 7) * 64;
        {
            const int kr = t >> 2;
            const int cb = (t & 3) * 16;
#pragma unroll
            for (int j = 0; j < 4; ++j) {
                float4 v = *(const float4*)&W_enc[(size_t)(k0 + kr) * F_SZ + n0 + cb + j * 4];
                tile[kr][cb + j * 4 + 0] = v.x;
                tile[kr][cb + j * 4 + 1] = v.y;
                tile[kr][cb + j * 4 + 2] = v.z;
                tile[kr][cb + j * 4 + 3] = v.w;
            }
        }
        __syncthreads();
        const int n = t >> 2;
#pragma unroll
        for (int cc = 0; cc < 2; ++cc) {
            const int ch = (t & 3) * 2 + cc;
            short8v h, l;
#pragma unroll
            for (int e = 0; e < 8; ++e) {
                short hh, ll;
                split_bf16(tile[ch * 8 + e][n], hh, ll);
                h[e] = hh; l[e] = ll;
            }
            size_t off = (size_t)(n0 + n) * D_SZ + k0 + ch * 8;
            *(short8v*)&Wh[off] = h;
            *(short8v*)&Wl[off] = l;
        }
    } else {
        const int id = bid - 2048;
        const int k0 = (id & 7) * 64;
        const int c0 = (id >> 3) * 64;
        for (int idx = t; idx < 64 * 64; idx += 256) {
            const int kr = idx >> 6;
            const int cc = idx & 63;
            tile[kr][cc] = (c0 + cc < C_SZ) ? W_fc[(size_t)(k0 + kr) * C_SZ + c0 + cc] : 0.0f;
        }
        __syncthreads();
        const int crow = t >> 2;
#pragma unroll
        for (int cc2 = 0; cc2 < 2; ++cc2) {
            const int ch = (t & 3) * 2 + cc2;
            short8v h, l;
#pragma unroll
            for (int e = 0; e < 8; ++e) {
                short hh, ll;
                split_bf16(tile[ch * 8 + e][crow], hh, ll);
                h[e] = hh; l[e] = ll;
            }
            size_t off = (size_t)(c0 + crow) * F_SZ + k0 + ch * 8;
            *(short8v*)&Wth[off] = h;
            *(short8v*)&Wtl[off] = l;
        }
    }
}

// ---------------------------------------------------------------------------
// gemm_ws128: P[ks] = A(128 x ksteps*64) @ B(.. x 128), bf16x3, split-K via
// blockIdx.z. 128x128 tile, double-buffered 128 KB LDS, gl_lds staging,
// XOR-swizzled (0 conflicts measured). New path: grid (4,16,4), ksteps=32.
// ---------------------------------------------------------------------------
__global__ __launch_bounds__(256, 1) void gemm_ws128(
    const short* __restrict__ Xh, const short* __restrict__ Xl,
    const short* __restrict__ Wh, const short* __restrict__ Wl,
    float* __restrict__ P, int ksteps)
{
    __shared__ __align__(16) short sAh[2][8192];
    __shared__ __align__(16) short sAl[2][8192];
    __shared__ __align__(16) short sBh[2][8192];
    __shared__ __align__(16) short sBl[2][8192];

    const int t = threadIdx.x;
    const int lane = t & 63;
    const int wave = t >> 6;
    const int nt = blockIdx.x;
    const int mt = blockIdx.y;
    const int ks = blockIdx.z;
    const int m0 = mt * 128;
    const int n0 = nt * 128;
    const int kbase = ks * ksteps * 64;

    const short* gbase =
        (wave == 0) ? Xh + (size_t)m0 * D_SZ :
        (wave == 1) ? Xl + (size_t)m0 * D_SZ :
        (wave == 2) ? Wh + (size_t)n0 * D_SZ :
                      Wl + (size_t)n0 * D_SZ;
    short* lb[2];
    lb[0] = (wave == 0) ? sAh[0] : (wave == 1) ? sAl[0] : (wave == 2) ? sBh[0] : sBl[0];
    lb[1] = (wave == 0) ? sAh[1] : (wave == 1) ? sAl[1] : (wave == 2) ? sBh[1] : sBl[1];
    const int lrow8 = lane >> 3;
    const int gchunkOff = ((lane & 7) ^ lrow8) * 8;
    const short* gsrc = gbase + (size_t)lrow8 * D_SZ + kbase + gchunkOff;

    const int mo = (wave >> 1) * 64;
    const int no = (wave & 1) * 64;
    const int lr = lane & 15;
    const int lkg = lane >> 4;
    const int x7 = lr & 7;
    const int sl0 = lkg ^ x7;
    const int sl1 = (4 + lkg) ^ x7;
    int aoff[4], boff[4];
#pragma unroll
    for (int f = 0; f < 4; ++f) {
        aoff[f] = (mo + 16 * f + lr) * 64;
        boff[f] = (no + 16 * f + lr) * 64;
    }

    f32x4 acc[4][4] = {};

#pragma unroll
    for (int j = 0; j < 16; ++j)
        gl_lds16(gsrc + (size_t)(8 * j) * D_SZ, lb[0] + j * 512);
    __syncthreads();

    int buf = 0;
    for (int s = 0; s < ksteps; ++s) {
        if (s + 1 < ksteps) {
            short* dst = lb[buf ^ 1];
            const short* g = gsrc + (s + 1) * 64;
#pragma unroll
            for (int j = 0; j < 16; ++j)
                gl_lds16(g + (size_t)(8 * j) * D_SZ, dst + j * 512);
        }
        const short* pAh = sAh[buf];
        const short* pAl = sAl[buf];
        const short* pBh = sBh[buf];
        const short* pBl = sBl[buf];
#pragma unroll
        for (int ksub = 0; ksub < 2; ++ksub) {
            const int sl = ksub ? sl1 : sl0;
            bf16x8 ah[4], al[4], bh[4], blo[4];
#pragma unroll
            for (int f = 0; f < 4; ++f) {
                ah[f]  = *(const bf16x8*)&pAh[aoff[f] + sl * 8];
                al[f]  = *(const bf16x8*)&pAl[aoff[f] + sl * 8];
            }
#pragma unroll
            for (int g = 0; g < 4; ++g) {
                bh[g]  = *(const bf16x8*)&pBh[boff[g] + sl * 8];
                blo[g] = *(const bf16x8*)&pBl[boff[g] + sl * 8];
            }
#pragma unroll
            for (int f = 0; f < 4; ++f)
#pragma unroll
                for (int g = 0; g < 4; ++g)
                    acc[f][g] = MFMA_BF16(ah[f], bh[g], acc[f][g], 0, 0, 0);
#pragma unroll
            for (int f = 0; f < 4; ++f)
#pragma unroll
                for (int g = 0; g < 4; ++g)
                    acc[f][g] = MFMA_BF16(ah[f], blo[g], acc[f][g], 0, 0, 0);
#pragma unroll
            for (int f = 0; f < 4; ++f)
#pragma unroll
                for (int g = 0; g < 4; ++g)
                    acc[f][g] = MFMA_BF16(al[f], bh[g], acc[f][g], 0, 0, 0);
        }
        __syncthreads();
        buf ^= 1;
    }

    float* Pout = P + (size_t)ks * (2048u * 512u);
#pragma unroll
    for (int f = 0; f < 4; ++f)
#pragma unroll
        for (int g = 0; g < 4; ++g) {
            const int col  = n0 + no + 16 * g + (lane & 15);
            const int row0 = m0 + mo + 16 * f + (lane >> 4) * 4;
#pragma unroll
            for (int r = 0; r < 4; ++r)
                Pout[(size_t)(row0 + r) * F_SZ + col] = acc[f][g][r];
        }
}

// ---------------------------------------------------------------------------
// fc_logits_fused2: A-tile = sum of 4 P slices (summed+split in-kernel);
// B from Wth/Wtl; bf16x3 MFMA; epilogue: +bias, logits store, packed-atomicMax
// masked argmax into labPack. nt==0 blocks also emit fp32 feats. grid (6,32).
// ---------------------------------------------------------------------------
__global__ __launch_bounds__(256) void fc_logits_fused2(
    const float* __restrict__ P,
    const short* __restrict__ Bh_g, const short* __restrict__ Bl_g,
    const float* __restrict__ bias, const float* __restrict__ partial_Y,
    float* __restrict__ logits, float* __restrict__ feats,
    unsigned long long* __restrict__ labPack)
{
    __shared__ __align__(16) short sAh[4096];
    __shared__ __align__(16) short sAl[4096];
    __shared__ __align__(16) short sBh[4096];
    __shared__ __align__(16) short sBl[4096];

    const int t = threadIdx.x;
    const int lane = t & 63;
    const int wave = t >> 6;
    const int n0 = blockIdx.x * 64;
    const int m0 = blockIdx.y * 64;
    const bool writeF = (blockIdx.x == 0);

    const int lrow8 = lane >> 3;
    const int colOff = ((lane & 7) ^ lrow8) * 8;

    const int mo = (wave >> 1) * 32;
    const int no = (wave & 1) * 32;
    const int lr = lane & 15;
    const int lkg = lane >> 4;
    const int x7 = lr & 7;
    const int sl0 = (0 + lkg) ^ x7;
    const int sl1 = (4 + lkg) ^ x7;
    const int ra0 = (mo + lr) * 64,      ra1 = (mo + 16 + lr) * 64;
    const int rb0 = (no + lr) * 64,      rb1 = (no + 16 + lr) * 64;
    const int a00 = ra0 + sl0 * 8, a01 = ra0 + sl1 * 8;
    const int a10 = ra1 + sl0 * 8, a11 = ra1 + sl1 * 8;
    const int b00 = rb0 + sl0 * 8, b01 = rb0 + sl1 * 8;
    const int b10 = rb1 + sl0 * 8, b11 = rb1 + sl1 * 8;

    f32x4 acc[2][2] = {};

    for (int s = 0; s < 8; ++s) {
        __syncthreads();
        if (wave < 2) {
            const short* gB = (wave == 0) ? Bh_g : Bl_g;
            short* lbase = (wave == 0) ? sBh : sBl;
#pragma unroll
            for (int j = 0; j < 8; ++j) {
                int row = n0 + lrow8 + 8 * j;
                gl_lds16(gB + (size_t)row * F_SZ + s * 64 + colOff, lbase + j * 512);
            }
        }
#pragma unroll
        for (int qq = 0; qq < 2; ++qq) {
            const int q = t + qq * 256;
            const int row = q >> 3;
            const int c = q & 7;
            const size_t gidx = (size_t)(m0 + row) * F_SZ + s * 64 + c * 8;
            float4 v0 = ((const float4*)&P[gidx])[0];
            float4 v1 = ((const float4*)&P[gidx])[1];
#pragma unroll
            for (int sl = 1; sl < 4; ++sl) {
                const float* Ps = P + (size_t)sl * (2048u * 512u);
                float4 u0 = ((const float4*)&Ps[gidx])[0];
                float4 u1 = ((const float4*)&Ps[gidx])[1];
                v0.x += u0.x; v0.y += u0.y; v0.z += u0.z; v0.w += u0.w;
                v1.x += u1.x; v1.y += u1.y; v1.z += u1.z; v1.w += u1.w;
            }
            float f[8] = {v0.x, v0.y, v0.z, v0.w, v1.x, v1.y, v1.z, v1.w};
            if (writeF) {
#pragma unroll
                for (int e = 0; e < 8; ++e) feats[gidx + e] = f[e];
            }
            bf16x8 h, l;
#pragma unroll
            for (int e = 0; e < 8; ++e) { short hh, ll; split_bf16(f[e], hh, ll); h[e] = hh; l[e] = ll; }
            const int slot = c ^ (row & 7);
            *(bf16x8*)&sAh[row * 64 + slot * 8] = h;
            *(bf16x8*)&sAl[row * 64 + slot * 8] = l;
        }
        __syncthreads();
        MFMA_BLOCK(a00, a10, b00, b10);
        MFMA_BLOCK(a01, a11, b01, b11);
    }

    const bool doArg = (m0 < B_SZ);
#pragma unroll
    for (int f = 0; f < 2; ++f) {
#pragma unroll
        for (int r = 0; r < 4; ++r) {
            const int row = m0 + mo + f * 16 + (lane >> 4) * 4 + r;
            unsigned long long best = 0;
#pragma unroll
            for (int g = 0; g < 2; ++g) {
                const int col = n0 + no + g * 16 + (lane & 15);
                if (col < C_SZ) {
                    const float v = acc[f][g][r] + bias[col];
                    logits[(size_t)row * C_SZ + col] = v;
                    if (doArg && partial_Y[(size_t)row * C_SZ + col] != 0.0f) {
                        unsigned long long p = ((unsigned long long)f2key(v) << 32)
                                             | (unsigned long long)(0xFFFFFFFFu - (unsigned)col);
                        if (p > best) best = p;
                    }
                }
            }
            if (doArg) {
#pragma unroll
                for (int m = 1; m < 16; m <<= 1) {
                    unsigned long long o = __shfl_xor(best, m);
                    if (o > best) best = o;
                }
                if ((lane & 15) == 0 && best != 0)
                    atomicMax(&labPack[row], best);
            }
        }
    }
}

// ---------------------------------------------------------------------------
// proto_scores_fused (R8 rewrite): per class c —
//   phase 1 (wave 0): 16 coalesced u64 loads of labPack + __ballot(label==c)
//     per 64-chunk; lane 0 unpacks set bits IN ORDER into LDS rowlist.
//     (replaces the 1024-iteration LDS-latency-bound scan — R7's 105 µs)
//   phase 2: EMA over only the m_c matching rows (order preserved), L2 renorm,
//     write new_proto; block 0 also writes labels_f.
//   phase 3: scores row, coalesced: wave w owns cols w, w+8, ...; lane l holds
//     nprow[8l..8l+8) in regs, reads Wth/Wtl[col][8l..8l+8) (1 KB/wave-load),
//     shuffle-reduce. (replaces lane-stride-1KB uncoalesced loads)
// grid 345, 512 threads.
// ---------------------------------------------------------------------------
__global__ __launch_bounds__(512) void proto_scores_fused(
    const unsigned long long* __restrict__ labPack,
    const float* __restrict__ feats_q,
    const float* __restrict__ proto,
    const short* __restrict__ Wth, const short* __restrict__ Wtl,
    const float* __restrict__ b_fc,
    float* __restrict__ new_proto, float* __restrict__ scores,
    float* __restrict__ labels_f)
{
    __shared__ int rowlist[B_SZ];
    __shared__ int mcount_s;
    __shared__ float nprow[F_SZ];
    __shared__ float red[8];
    __shared__ float rinv_s;
    const int c = blockIdx.x;
    const int t = threadIdx.x;
    const int lane = t & 63;
    const int w = t >> 6;

    // block 0: decode + write labels_f (2 coalesced reads/thread)
    if (c == 0) {
#pragma unroll
        for (int j = 0; j < 2; ++j) {
            const int i = t + j * 512;
            int li = (int)(0xFFFFFFFFu - (unsigned)(labPack[i] & 0xFFFFFFFFull));
            labels_f[i] = (float)li;
        }
    }

    // phase 1: wave 0 finds matching rows via ballot (in row order)
    if (w == 0) {
        int k = 0;
#pragma unroll
        for (int ch = 0; ch < 16; ++ch) {
            unsigned long long pk = labPack[ch * 64 + lane];
            int li = (int)(0xFFFFFFFFu - (unsigned)(pk & 0xFFFFFFFFull));
            unsigned long long mask = __ballot(li == c);
            if (lane == 0) {
                while (mask) {
                    int p = __builtin_ctzll(mask);
                    mask &= mask - 1;
                    rowlist[k++] = ch * 64 + p;
                }
            }
            k = __shfl(k, 0);
        }
        if (lane == 0) mcount_s = k;
    }
    __syncthreads();
    const int m = mcount_s;

    // phase 2: EMA over the m matching rows (reference order), renorm
    float val = proto[(size_t)c * F_SZ + t];
    for (int k = 0; k < m; ++k)
        val = PROTO_W * val + (1.0f - PROTO_W) * feats_q[(size_t)rowlist[k] * F_SZ + t];

    float sq = val * val;
#pragma unroll
    for (int off = 32; off; off >>= 1) sq += __shfl_down(sq, off);
    if ((t & 63) == 0) red[t >> 6] = sq;
    __syncthreads();
    if (t == 0) {
        float s = 0.0f;
#pragma unroll
        for (int ww = 0; ww < 8; ++ww) s += red[ww];
        rinv_s = 1.0f / sqrtf(s);
    }
    __syncthreads();
    const float v = val * rinv_s;
    new_proto[(size_t)c * F_SZ + t] = v;
    nprow[t] = v;
    __syncthreads();

    // phase 3: scores[c][col] = b_fc[col] + nprow . (Wth[col]+Wtl[col]), coalesced
    float np8[8];
#pragma unroll
    for (int j = 0; j < 8; ++j) np8[j] = nprow[lane * 8 + j];
    for (int col = w; col < C_SZ; col += 8) {
        const short8v h = *(const short8v*)&Wth[(size_t)col * F_SZ + lane * 8];
        const short8v l = *(const short8v*)&Wtl[(size_t)col * F_SZ + lane * 8];
        float p = 0.0f;
#pragma unroll
        for (int j = 0; j < 8; ++j)
            p += np8[j] * (bf16_f32(h[j]) + bf16_f32(l[j]));
#pragma unroll
        for (int off = 32; off; off >>= 1) p += __shfl_down(p, off);
        if (lane == 0) scores[(size_t)c * C_SZ + col] = p + b_fc[col];
    }
}

// ===========================================================================
// OLD-path kernels (R6-proven fallback; used when ws < WS2_NEED)
// ===========================================================================
__global__ __launch_bounds__(256) void reduce_feats_split(
    const float* __restrict__ P, float* __restrict__ feats,
    short* __restrict__ Fh, short* __restrict__ Fl,
    const float* __restrict__ W_fc,
    short* __restrict__ Wth, short* __restrict__ Wtl)
{
    const int bid = blockIdx.x;
    const int t = threadIdx.x;
    if (bid < 1024) {
        const int n4 = (2048 * 512) / 4;
        const float* P1 = P + 2048 * 512;
        for (int i4 = bid * 256 + t; i4 < n4; i4 += 1024 * 256) {
            float4 a = ((const float4*)P)[i4];
            float4 b = ((const float4*)P1)[i4];
            float v[4] = {a.x + b.x, a.y + b.y, a.z + b.z, a.w + b.w};
            short4v h, l;
            short hh, ll;
#pragma unroll
            for (int e = 0; e < 4; ++e) {
                feats[i4 * 4 + e] = v[e];
                split_bf16(v[e], hh, ll); h[e] = hh; l[e] = ll;
            }
            ((short4v*)Fh)[i4] = h;
            ((short4v*)Fl)[i4] = l;
        }
    } else {
        __shared__ float tile[64][65];
        const int id = bid - 1024;
        const int k0 = (id & 7) * 64;
        const int c0 = (id >> 3) * 64;
        for (int idx = t; idx < 64 * 64; idx += 256) {
            const int kr = idx >> 6;
            const int cc = idx & 63;
            tile[kr][cc] = (c0 + cc < C_SZ) ? W_fc[(size_t)(k0 + kr) * C_SZ + c0 + cc] : 0.0f;
        }
        __syncthreads();
        const int crow = t >> 2;
#pragma unroll
        for (int cc2 = 0; cc2 < 2; ++cc2) {
            const int ch = (t & 3) * 2 + cc2;
            short8v h, l;
#pragma unroll
            for (int e = 0; e < 8; ++e) {
                short hh, ll;
                split_bf16(tile[ch * 8 + e][crow], hh, ll);
                h[e] = hh; l[e] = ll;
            }
            size_t off = (size_t)(c0 + crow) * F_SZ + k0 + ch * 8;
            *(short8v*)&Wth[off] = h;
            *(short8v*)&Wtl[off] = l;
        }
    }
}

__global__ __launch_bounds__(256) void gemm_fc(
    const short* __restrict__ Ah, const short* __restrict__ Al,
    const short* __restrict__ Bh, const short* __restrict__ Bl,
    const float* __restrict__ bias, float* __restrict__ Cout, int M)
{
    __shared__ __align__(16) short sAh[4096];
    __shared__ __align__(16) short sAl[4096];
    __shared__ __align__(16) short sBh[4096];
    __shared__ __align__(16) short sBl[4096];

    const int t = threadIdx.x;
    const int lane = t & 63;
    const int wave = t >> 6;
    const int n0 = blockIdx.x * 64;
    const int m0 = blockIdx.y * 64;

    const int lrow8 = lane >> 3;
    const int colOff = ((lane & 7) ^ lrow8) * 8;

    short* lbase = (wave == 0) ? sAh : (wave == 1) ? sAl : (wave == 2) ? sBh : sBl;
    const short* gA = (wave == 1) ? Al : Ah;
    const short* gB = (wave == 3) ? Bl : Bh;
    const bool isA = wave < 2;

    const int mo = (wave >> 1) * 32;
    const int no = (wave & 1) * 32;
    const int lr = lane & 15;
    const int lkg = lane >> 4;
    const int x7 = lr & 7;
    const int sl0 = (0 + lkg) ^ x7;
    const int sl1 = (4 + lkg) ^ x7;
    const int ra0 = (mo + lr) * 64,      ra1 = (mo + 16 + lr) * 64;
    const int rb0 = (no + lr) * 64,      rb1 = (no + 16 + lr) * 64;
    const int a00 = ra0 + sl0 * 8, a01 = ra0 + sl1 * 8;
    const int a10 = ra1 + sl0 * 8, a11 = ra1 + sl1 * 8;
    const int b00 = rb0 + sl0 * 8, b01 = rb0 + sl1 * 8;
    const int b10 = rb1 + sl0 * 8, b11 = rb1 + sl1 * 8;

    f32x4 acc[2][2] = {};

    for (int s = 0; s < 8; ++s) {
        __syncthreads();
        if (isA) {
#pragma unroll
            for (int j = 0; j < 8; ++j) {
                int row = m0 + lrow8 + 8 * j;
                if (row > M - 1) row = M - 1;
                gl_lds16(gA + (size_t)row * F_SZ + s * 64 + colOff, lbase + j * 512);
            }
        } else {
#pragma unroll
            for (int j = 0; j < 8; ++j) {
                int row = n0 + lrow8 + 8 * j;
                gl_lds16(gB + (size_t)row * F_SZ + s * 64 + colOff, lbase + j * 512);
            }
        }
        __syncthreads();
        MFMA_BLOCK(a00, a10, b00, b10);
        MFMA_BLOCK(a01, a11, b01, b11);
    }

#pragma unroll
    for (int f = 0; f < 2; ++f)
#pragma unroll
        for (int g = 0; g < 2; ++g) {
            const int col  = n0 + no + g * 16 + (lane & 15);
            if (col >= C_SZ) continue;
            const float bb = bias[col];
            const int row0 = m0 + mo + f * 16 + (lane >> 4) * 4;
#pragma unroll
            for (int r = 0; r < 4; ++r) {
                const int row = row0 + r;
                if (row < M)
                    Cout[(size_t)row * C_SZ + col] = acc[f][g][r] + bb;
            }
        }
}

__global__ __launch_bounds__(64) void argmax_labels(
    const float* __restrict__ logits, const float* __restrict__ partial_Y,
    float* __restrict__ labels_f)
{
    const int i = blockIdx.x;
    const int lane = threadIdx.x;
    float best = -FLT_MAX;
    int bidx = C_SZ;
    for (int c = lane; c < C_SZ; c += 64) {
        if (partial_Y[(size_t)i * C_SZ + c] != 0.0f) {
            float v = logits[(size_t)i * C_SZ + c];
            if (v > best || (v == best && c < bidx)) { best = v; bidx = c; }
        }
    }
#pragma unroll
    for (int off = 32; off; off >>= 1) {
        float ov = __shfl_down(best, off);
        int oi = __shfl_down(bidx, off);
        if (ov > best || (ov == best && oi < bidx)) { best = ov; bidx = oi; }
    }
    if (lane == 0) labels_f[i] = (float)bidx;
}

__global__ __launch_bounds__(512) void proto_update(
    const float* __restrict__ labels_f, const float* __restrict__ feats_q,
    const float* __restrict__ proto, float* __restrict__ new_proto,
    short* __restrict__ NPh, short* __restrict__ NPl)
{
    __shared__ int lab[B_SZ];
    __shared__ float red[8];
    __shared__ float rinv_s;
    const int c = blockIdx.x;
    const int t = threadIdx.x;
    for (int i = t; i < B_SZ; i += 512) lab[i] = (int)labels_f[i];
    __syncthreads();
    float val = proto[(size_t)c * F_SZ + t];
    for (int i = 0; i < B_SZ; ++i) {
        if (lab[i] == c)
            val = PROTO_W * val + (1.0f - PROTO_W) * feats_q[(size_t)i * F_SZ + t];
    }
    float sq = val * val;
#pragma unroll
    for (int off = 32; off; off >>= 1) sq += __shfl_down(sq, off);
    if ((t & 63) == 0) red[t >> 6] = sq;
    __syncthreads();
    if (t == 0) {
        float s = 0.0f;
#pragma unroll
        for (int w = 0; w < 8; ++w) s += red[w];
        rinv_s = 1.0f / sqrtf(s);
    }
    __syncthreads();
    const float v = val * rinv_s;
    new_proto[(size_t)c * F_SZ + t] = v;
    if (NPh) {
        short hh, ll;
        split_bf16(v, hh, ll);
        NPh[(size_t)c * F_SZ + t] = hh;
        NPl[(size_t)c * F_SZ + t] = ll;
    }
}

// ---------------------------------------------------------------------------
extern "C" void kernel_launch(void* const* d_in, const int* in_sizes, int n_in,
                              void* d_out, int out_size, void* d_ws, size_t ws_size,
                              hipStream_t stream)
{
    const float* img_q     = (const float*)d_in[0];
    const float* img_q1    = (const float*)d_in[1];
    const float* partial_Y = (const float*)d_in[2];
    const float* W_enc     = (const float*)d_in[3];
    const float* W_fc      = (const float*)d_in[4];
    const float* b_fc      = (const float*)d_in[5];
    const float* proto     = (const float*)d_in[6];

    float* out       = (float*)d_out;
    float* logits    = out;            // [2048][345]
    float* new_proto = out + 706560;   // [345][512]
    float* scores    = out + 883200;   // [345][345]
    float* labels_f  = out + 1002225;  // [1024]
    float* feats     = out + 1003249;  // [2048][512]

    char* ws = (char*)d_ws;
    short* Xh = (short*)(ws + WS_XH);
    short* Xl = (short*)(ws + WS_XL);
    short* Wh = (short*)(ws + WS_WH);
    short* Wl = (short*)(ws + WS_WL);
    float* P  = (float*)(ws + WS_P);

    if (ws_size >= (size_t)WS2_NEED) {
        short* Wth = (short*)(ws + WS2_WFH);
        short* Wtl = (short*)(ws + WS2_WFL);
        unsigned long long* labPack = (unsigned long long*)(ws + WS2_LAB);

        hipMemsetAsync(labPack, 0, B_SZ * sizeof(unsigned long long), stream);
        hipLaunchKernelGGL(convert_all, dim3(2096), dim3(256), 0, stream,
                           img_q, img_q1, W_enc, W_fc, Xh, Xl, Wh, Wl, Wth, Wtl);
        hipLaunchKernelGGL(gemm_ws128, dim3(4, 16, 4), dim3(256), 0, stream,
                           Xh, Xl, Wh, Wl, P, 32);
        hipLaunchKernelGGL(fc_logits_fused2, dim3(6, 32), dim3(256), 0, stream,
                           P, Wth, Wtl, b_fc, partial_Y, logits, feats, labPack);
        hipLaunchKernelGGL(proto_scores_fused, dim3(345), dim3(512), 0, stream,
                           labPack, feats, proto, Wth, Wtl, b_fc,
                           new_proto, scores, labels_f);
    } else {
        short* Fh  = (short*)(ws + WS_FH);
        short* Fl  = (short*)(ws + WS_FL);
        short* Wth = (short*)(ws + WS_WFH);
        short* Wtl = (short*)(ws + WS_WFL);
        short* NPh = (short*)(ws + WS_NPH);
        short* NPl = (short*)(ws + WS_NPL);

        hipLaunchKernelGGL(convert_all, dim3(2048), dim3(256), 0, stream,
                           img_q, img_q1, W_enc, W_fc, Xh, Xl, Wh, Wl,
                           (short*)nullptr, (short*)nullptr);
        hipLaunchKernelGGL(gemm_ws128, dim3(4, 16, 2), dim3(256), 0, stream,
                           Xh, Xl, Wh, Wl, P, 64);
        hipLaunchKernelGGL(reduce_feats_split, dim3(1072), dim3(256), 0, stream,
                           P, feats, Fh, Fl, W_fc, Wth, Wtl);
        hipLaunchKernelGGL(gemm_fc, dim3(6, 32), dim3(256), 0, stream,
                           Fh, Fl, Wth, Wtl, b_fc, logits, 2048);
        hipLaunchKernelGGL(argmax_labels, dim3(1024), dim3(64), 0, stream,
                           logits, partial_Y, labels_f);
        hipLaunchKernelGGL(proto_update, dim3(345), dim3(512), 0, stream,
                           labels_f, feats, proto, new_proto, NPh, NPl);
        hipLaunchKernelGGL(gemm_fc, dim3(6, 6), dim3(256), 0, stream,
                           NPh, NPl, Wth, Wtl, b_fc, scores, C_SZ);
    }
}